// Round 13
// baseline (247.563 us; speedup 1.0000x reference)
//
#include <hip/hip_runtime.h>
#include <hip/hip_bf16.h>
#include <cstdint>
#include <cstddef>

// ---------------------------------------------------------------------------
// UWBPoseEncoder: B=32, M=2048, T=8, H=64
// prep-weights -> encoder(h1,h2,q,k,v MFMA) -> flash-attn (32x32 swapped,
// fixed-reference exp2 softmax, XCD swizzle, 2 q-tiles/wave, DOUBLE buffer
// -> 4 independent blocks/CU) -> fused a1+seg partials (LDS feat tile) -> head
// ---------------------------------------------------------------------------

typedef short s16x8 __attribute__((ext_vector_type(8)));
typedef float f32x4 __attribute__((ext_vector_type(4)));
typedef float f32x16 __attribute__((ext_vector_type(16)));

#define LOG2E  1.4426950408889634f
#define QSCALE 0.18033688011112042f   /* 0.125 * log2(e) */

__device__ __forceinline__ unsigned short f2bf(float f) {
    unsigned u = __builtin_bit_cast(unsigned, f);
    u += 0x7fffu + ((u >> 16) & 1u);          // RNE truncate to bf16
    return (unsigned short)(u >> 16);
}

__device__ __forceinline__ unsigned cvtpk(float lo, float hi) {
    unsigned r;
    asm("v_cvt_pk_bf16_f32 %0, %1, %2" : "=v"(r) : "v"(lo), "v"(hi));
    return r;
}

__device__ __forceinline__ float exp2_raw(float x) {
    float r;
    asm("v_exp_f32 %0, %1" : "=v"(r) : "v"(x));
    return r;
}

// swaps upper 32 lanes of a with lower 32 lanes of b
#define PLSWAP(a, b) asm("v_permlane32_swap_b32 %0, %1" : "+v"(a), "+v"(b))

// drain-vmcnt barrier
#define WAITBAR0() do { \
    asm volatile("s_waitcnt vmcnt(0)\n\ts_barrier" ::: "memory"); \
    __builtin_amdgcn_sched_barrier(0); \
} while (0)

__device__ __forceinline__ void gload_lds16(const void* g, void* l) {
    __builtin_amdgcn_global_load_lds((const __attribute__((address_space(1))) void*)g,
                                     (__attribute__((address_space(3))) void*)l, 16, 0, 0);
}

#define MFMA16(a, b, c) __builtin_amdgcn_mfma_f32_16x16x32_bf16((a), (b), (c), 0, 0, 0)
#define MFMA32(a, b, c) __builtin_amdgcn_mfma_f32_32x32x16_bf16((a), (b), (c), 0, 0, 0)

// ---------------- K0: weight prep (transpose to [out][in], bf16) ------------
__global__ void k_prep(const float* __restrict__ w2, const float* __restrict__ qw,
                       const float* __restrict__ kw, const float* __restrict__ vw,
                       unsigned short* __restrict__ wt)
{
    int tid = blockIdx.x * 256 + threadIdx.x;   // 2048 threads
    for (int idx = tid; idx < 4096; idx += 2048) {
        int o = idx >> 6, i = idx & 63;
        wt[idx]         = f2bf(w2[i * 64 + o]);
        wt[4096 + idx]  = f2bf(qw[i * 64 + o] * QSCALE);
        wt[8192 + idx]  = f2bf(kw[i * 64 + o]);
        wt[12288 + idx] = f2bf(vw[i * 64 + o]);
    }
}

// ---------------- K1: encoder + QKV -----------------------------------------
__global__ __launch_bounds__(256)
void k_encode(const float* __restrict__ meas, const float* __restrict__ w1,
              const float* __restrict__ b1, const float* __restrict__ b2,
              const float* __restrict__ qb, const float* __restrict__ kb,
              const float* __restrict__ vb,
              const unsigned short* __restrict__ wt,
              float* __restrict__ feat,
              unsigned short* __restrict__ qbf, unsigned short* __restrict__ kbf,
              unsigned short* __restrict__ vt)
{
    __shared__ __align__(16) unsigned short hbuf[4][1152];   // 16 rows x 72
    int tid = threadIdx.x;
    int w = tid >> 6, lane = tid & 63;
    int g = lane >> 4, c16 = lane & 15;
    int m0 = (blockIdx.x * 4 + w) * 16;          // global row base (b*2048+m)
    int b  = m0 >> 11;
    unsigned short* hb = hbuf[w];
    int vrow = lane >> 2, vseg = lane & 3;       // vectorized-store mapping

    // ---- h1 directly in A-fragment layout ----
    float x[5];
    const float* xr = meas + (size_t)(m0 + c16) * 5;
#pragma unroll
    for (int i = 0; i < 5; ++i) x[i] = xr[i];
    s16x8 aH[2];
#pragma unroll
    for (int s = 0; s < 2; ++s) {
#pragma unroll
        for (int jj = 0; jj < 8; ++jj) {
            int j = 8 * g + jj + 32 * s;
            float acc = b1[j];
#pragma unroll
            for (int i = 0; i < 5; ++i) acc += x[i] * w1[i * 64 + j];
            aH[s][jj] = (short)f2bf(fmaxf(acc, 0.f));
        }
    }

    const f32x4 zero = {0.f, 0.f, 0.f, 0.f};
    f32x4 c[4];

    // ---- h2 = relu(h1 @ W2 + b2) ----
#pragma unroll
    for (int dt = 0; dt < 4; ++dt) {
        c[dt] = zero;
#pragma unroll
        for (int s = 0; s < 2; ++s) {
            s16x8 bf = *(const s16x8*)(wt + (c16 + 16 * dt) * 64 + 32 * s + 8 * g);
            c[dt] = MFMA16(aH[s], bf, c[dt]);
        }
    }
#pragma unroll
    for (int dt = 0; dt < 4; ++dt) {
        int d = c16 + 16 * dt;
        float bias = b2[d];
#pragma unroll
        for (int r = 0; r < 4; ++r) {
            float v = fmaxf(c[dt][r] + bias, 0.f);
            feat[(size_t)(m0 + 4 * g + r) * 64 + d] = v;
            hb[(4 * g + r) * 72 + d] = f2bf(v);
        }
    }
    s16x8 aF[2];
#pragma unroll
    for (int s = 0; s < 2; ++s)
        aF[s] = *(const s16x8*)(hb + c16 * 72 + 32 * s + 8 * g);

    auto gemmW = [&](const unsigned short* wmat, f32x4* cc) {
#pragma unroll
        for (int dt = 0; dt < 4; ++dt) {
            cc[dt] = zero;
#pragma unroll
            for (int s = 0; s < 2; ++s) {
                s16x8 bf = *(const s16x8*)(wmat + (c16 + 16 * dt) * 64 + 32 * s + 8 * g);
                cc[dt] = MFMA16(aF[s], bf, cc[dt]);
            }
        }
    };
    // write C-tile (plus bias) to wave-private LDS, then 2x16B coalesced store
    auto storeV = [&](const float* bias4, unsigned short* dstbase) {
#pragma unroll
        for (int dt = 0; dt < 4; ++dt) {
            int d = c16 + 16 * dt;
#pragma unroll
            for (int r = 0; r < 4; ++r)
                hb[(4 * g + r) * 72 + d] = f2bf(c[dt][r] + bias4[dt]);
        }
        s16x8 o0 = *(const s16x8*)(hb + vrow * 72 + vseg * 16);
        s16x8 o1 = *(const s16x8*)(hb + vrow * 72 + vseg * 16 + 8);
        unsigned short* dst = dstbase + (size_t)(m0 + vrow) * 64 + vseg * 16;
        *(s16x8*)dst = o0;
        *(s16x8*)(dst + 8) = o1;
    };

    float bias4[4];
    // ---- q (pre-scaled) ----
    gemmW(wt + 4096, c);
#pragma unroll
    for (int dt = 0; dt < 4; ++dt) bias4[dt] = qb[c16 + 16 * dt] * QSCALE;
    storeV(bias4, qbf);
    // ---- k ----
    gemmW(wt + 8192, c);
#pragma unroll
    for (int dt = 0; dt < 4; ++dt) bias4[dt] = kb[c16 + 16 * dt];
    storeV(bias4, kbf);
    // ---- v: compute, transpose through LDS, store vt[b][d][m] ----
    gemmW(wt + 12288, c);
#pragma unroll
    for (int dt = 0; dt < 4; ++dt) {
        int d = c16 + 16 * dt;
        float bias = vb[d];
#pragma unroll
        for (int r = 0; r < 4; ++r)
            hb[(4 * g + r) * 72 + d] = f2bf(c[dt][r] + bias);
    }
    unsigned short tvv[16];
#pragma unroll
    for (int mr = 0; mr < 16; ++mr) tvv[mr] = hb[mr * 72 + lane];   // column d=lane
    s16x8 v0, v1;
#pragma unroll
    for (int e2 = 0; e2 < 8; ++e2) { v0[e2] = (short)tvv[e2]; v1[e2] = (short)tvv[8 + e2]; }
    unsigned short* dst = vt + ((size_t)b * 64 + lane) * 2048 + (m0 & 2047);
    *(s16x8*)dst = v0;
    *(s16x8*)(dst + 8) = v1;
}

// ---------------- K2: flash attention (32x32 swapped, 2 q-tiles/wave) -------
// 512 blocks x 256 thr (4 waves). Double-buffered staging (32KB) -> 4
// independent blocks/CU (16 waves/CU): cross-block overlap hides the per-iter
// vmcnt(0) drain + phase serialization. XCD swizzle, fixed-reference softmax.
__global__ __launch_bounds__(256, 4)
void k_attn(const unsigned short* __restrict__ qbf, const unsigned short* __restrict__ kbf,
            const unsigned short* __restrict__ vt, float* __restrict__ feat)
{
    __shared__ __align__(16) char smem[37888];
    // staging: K[2][64][64]bf16 @0 (2x8KB), V[2][64][64]bf16 @16384 (2x8KB)
    // merge (after loop): Om[4][64][36]f32 @0 (36864B), Ml[4][32]f32 @36864

    int tid = threadIdx.x;
    int w_ = tid >> 6, lane = tid & 63;
    int h = lane >> 5, c32 = lane & 31;
    int jhalf = w_ & 1, tpair = w_ >> 1;
    int bid = (int)blockIdx.x;
    bid = (bid & 7) * 64 + (bid >> 3);           // XCD-aware swizzle (bijective)
    int b = bid >> 4;
    int q0g = (bid & 15) * 128;                  // block covers 128 queries
    size_t rowbase = (size_t)b * 2048;

    const unsigned short* kbf_b = kbf + rowbase * 64;
    const unsigned short* vt_b  = vt + (size_t)b * 64 * 2048;

    // Q fragments (B-operand) for 2 tiles: qf[ti][st]
    s16x8 qf[2][4];
#pragma unroll
    for (int ti = 0; ti < 2; ++ti) {
        const unsigned short* qp =
            qbf + (rowbase + q0g + (2 * tpair + ti) * 32 + c32) * 64 + 8 * h;
#pragma unroll
        for (int st = 0; st < 4; ++st)
            qf[ti][st] = *(const s16x8*)(qp + 16 * st);
    }

    f32x16 zero16;
#pragma unroll
    for (int i = 0; i < 16; ++i) zero16[i] = 0.f;

    f32x16 oA[2], oB[2];                          // o[tile][dt], static names
#pragma unroll
    for (int dt = 0; dt < 2; ++dt)
#pragma unroll
        for (int i = 0; i < 16; ++i) { oA[dt][i] = 0.f; oB[dt][i] = 0.f; }
    float llA = 0.f, llB = 0.f;

    // staging: 256 threads cover 512 granules (64 rows x 8 x 16B) per matrix,
    // two halves; swizzled source -> linear LDS dest (e = half*256 + tid).
    int r0 = tid >> 3,         g0 = (tid & 7) ^ (r0 & 7);
    int r1 = (tid + 256) >> 3, g1 = (tid & 7) ^ (r1 & 7);
    const unsigned short* gkA = kbf_b + r0 * 64 + g0 * 8;
    const unsigned short* gkB = kbf_b + r1 * 64 + g1 * 8;
    const unsigned short* gvA = vt_b + (size_t)r0 * 2048 + g0 * 8;
    const unsigned short* gvB = vt_b + (size_t)r1 * 2048 + g1 * 8;

    auto stage = [&](int kt, int buf) {
        char* kd = smem + buf * 8192 + w_ * 1024;
        char* vd = smem + 16384 + buf * 8192 + w_ * 1024;
        gload_lds16(gkA + (size_t)kt * 4096, kd);
        gload_lds16(gkB + (size_t)kt * 4096, kd + 4096);
        gload_lds16(gvA + kt * 64, vd);
        gload_lds16(gvB + kt * 64, vd + 4096);
    };

    int swz = c32 & 7;
    int krow = 32 * jhalf + c32;

    auto compute = [&](int buf) {
        const char* Kb = smem + buf * 8192;
        const char* Vb = smem + 16384 + buf * 8192;

        s16x8 kf[4], vf[2][2];
#pragma unroll
        for (int st = 0; st < 4; ++st)
            kf[st] = *(const s16x8*)(Kb + krow * 128 + (((2 * st + h) ^ swz) * 16));
#pragma unroll
        for (int ks = 0; ks < 2; ++ks)
#pragma unroll
            for (int dt = 0; dt < 2; ++dt)
                vf[ks][dt] = *(const s16x8*)(Vb + (32 * dt + c32) * 128 +
                                             (((4 * jhalf + 2 * ks + h) ^ swz) * 16));

#pragma unroll
        for (int ti = 0; ti < 2; ++ti) {
            f32x16* o = ti ? oB : oA;
            float& ll = ti ? llB : llA;

            __builtin_amdgcn_s_setprio(1);
            f32x16 sc = MFMA32(kf[0], qf[ti][0], zero16);
#pragma unroll
            for (int st = 1; st < 4; ++st)
                sc = MFMA32(kf[st], qf[ti][st], sc);
            __builtin_amdgcn_s_setprio(0);

            float p[16];
#pragma unroll
            for (int i = 0; i < 16; ++i) p[i] = exp2_raw(sc[i]);

            float s;
            {
                float a0 = p[0] + p[1],  a1 = p[2] + p[3],  a2 = p[4] + p[5],  a3 = p[6] + p[7];
                float a4 = p[8] + p[9],  a5 = p[10] + p[11], a6 = p[12] + p[13], a7 = p[14] + p[15];
                float b0 = a0 + a1, b1 = a2 + a3, b2 = a4 + a5, b3 = a6 + a7;
                s = (b0 + b1) + (b2 + b3);
            }
            {
                float s1 = s, s2 = s;
                PLSWAP(s1, s2);
                s = s1 + s2;
            }
            ll += s;

            unsigned u[8];
#pragma unroll
            for (int k2 = 0; k2 < 8; ++k2) u[k2] = cvtpk(p[2 * k2], p[2 * k2 + 1]);

            __builtin_amdgcn_s_setprio(1);
#pragma unroll
            for (int ks = 0; ks < 2; ++ks) {
                unsigned a0 = u[4 * ks + 0], b0 = u[4 * ks + 2];
                unsigned a1 = u[4 * ks + 1], b1 = u[4 * ks + 3];
                PLSWAP(a0, b0);
                PLSWAP(a1, b1);
                union { unsigned uu[4]; s16x8 v; } pa;
                pa.uu[0] = a0; pa.uu[1] = a1; pa.uu[2] = b0; pa.uu[3] = b1;
#pragma unroll
                for (int dt = 0; dt < 2; ++dt)
                    o[dt] = MFMA32(pa.v, vf[ks][dt], o[dt]);
            }
            __builtin_amdgcn_s_setprio(0);
        }
    };

    // prologue
    stage(0, 0);
    WAITBAR0();

#pragma unroll 2
    for (int kt = 0; kt < 31; ++kt) {
        stage(kt + 1, (kt + 1) & 1);   // buffer (kt+1)&1 was fully read in iter kt-1
        compute(kt & 1);
        WAITBAR0();                    // next tile's loads landed; all reads of kt done
    }
    compute(31 & 1);
    __syncthreads();     // LDS reuse for merge

    // ---- merge split-K pairs (w, w^1) and write feat += O/l ----
    float* Om = (float*)smem;                 // [4 tiles][64][36]
    float* Ml = (float*)(smem + 36864);       // [4 tiles][32]
    if (jhalf) {
#pragma unroll
        for (int ti = 0; ti < 2; ++ti) {
            int tg = 2 * tpair + ti;
            const f32x16* o = ti ? oB : oA;
#pragma unroll
            for (int dt = 0; dt < 2; ++dt)
#pragma unroll
                for (int rg = 0; rg < 4; ++rg) {
                    f32x4 vv;
#pragma unroll
                    for (int r = 0; r < 4; ++r) vv[r] = o[dt][4 * rg + r];
                    *(f32x4*)&Om[(tg * 64 + 32 * dt + c32) * 36 + 8 * rg + 4 * h] = vv;
                }
            if (h == 0) Ml[tg * 32 + c32] = ti ? llB : llA;
        }
    }
    __syncthreads();
    if (!jhalf) {
#pragma unroll
        for (int ti = 0; ti < 2; ++ti) {
            int tg = 2 * tpair + ti;
            const f32x16* o = ti ? oB : oA;
            float ll = ti ? llB : llA;
            float l1 = Ml[tg * 32 + c32];
            float f = 1.f / (ll + l1);
            float fr[16];
#pragma unroll
            for (int r = 0; r < 16; ++r) {
                int qrow = (r & 3) + 8 * (r >> 2) + 4 * h;
                fr[r] = __shfl(f, qrow);
            }
#pragma unroll
            for (int dt = 0; dt < 2; ++dt)
#pragma unroll
                for (int rg = 0; rg < 4; ++rg) {
                    f32x4 pv = *(const f32x4*)&Om[(tg * 64 + 32 * dt + c32) * 36 + 8 * rg + 4 * h];
#pragma unroll
                    for (int r = 0; r < 4; ++r) {
                        int rr = 4 * rg + r;
                        int qrow = r + 8 * rg + 4 * h;
                        size_t fi = (rowbase + q0g + tg * 32 + qrow) * 64 + 32 * dt + c32;
                        feat[fi] += (o[dt][rr] + pv[r]) * fr[rr];
                    }
                }
        }
    }
}

// ---------------- K3: fused a1 MLP + unnormalized tag partials --------------
// 512 blocks = 32 batches x 16 chunks of 128 rows. feat tile staged in LDS
// during phase A; phase B reads LDS instead of re-reading 16MB from HBM.
__global__ __launch_bounds__(256)
void k_a1tag(const float* __restrict__ feat, const int* __restrict__ map,
             const float* __restrict__ a1w1, const float* __restrict__ b1,
             const float* __restrict__ w2, const float* __restrict__ b2,
             float* __restrict__ part1, float* __restrict__ part0)
{
    __shared__ float fls[128][68];      // feat tile (pad 68: b128 writes spread)
    __shared__ float psum[128][33];
    __shared__ float es[128];
    __shared__ float accv[4][8][64];
    __shared__ float s0red[4][8];

    int b = blockIdx.x >> 4;
    int c = blockIdx.x & 15;
    int tid = threadIdx.x, lane = tid & 63, w = tid >> 6;
    int m0 = c * 128;
    const int* mp = map + b * 2048 + m0;
    const float* fbase = feat + ((size_t)b * 2048 + m0) * 64;

    // phase A: a1 for 128 rows, k-split across thread halves (kh = 0/1);
    // feat tile copied to LDS on the way through.
    {
        int r = tid & 127, kh = tid >> 7;
        const f32x4* fr4 = (const f32x4*)(fbase + (size_t)r * 64 + kh * 32);
        float acc[32];
#pragma unroll
        for (int j = 0; j < 32; ++j) acc[j] = kh ? 0.f : b1[j];
#pragma unroll
        for (int kc = 0; kc < 8; ++kc) {
            f32x4 fv = fr4[kc];
            *(f32x4*)&fls[r][kh * 32 + kc * 4] = fv;
#pragma unroll
            for (int ki = 0; ki < 4; ++ki) {
                const float* wr = a1w1 + (kh * 32 + kc * 4 + ki) * 32;   // [k][j]
#pragma unroll
                for (int j = 0; j < 32; ++j)
                    acc[j] = fmaf(fv[ki], wr[j], acc[j]);
            }
        }
        if (kh) {
#pragma unroll
            for (int j = 0; j < 32; ++j) psum[r][j] = acc[j];
        }
        __syncthreads();
        if (!kh) {
            float s = b2[0];
#pragma unroll
            for (int j = 0; j < 32; ++j)
                s += fmaxf(acc[j] + psum[r][j], 0.f) * w2[j];
            es[r] = exp2_raw(s * LOG2E);
        }
    }
    __syncthreads();

    // phase B: unnormalized weighted-feat partials per tag (feat from LDS)
    float tacc[8], s0t[8];
#pragma unroll
    for (int t = 0; t < 8; ++t) { tacc[t] = 0.f; s0t[t] = 0.f; }
    for (int mi = w; mi < 128; mi += 4) {
        int tg = mp[mi];
        float e = es[mi];
        float wf = e * fls[mi][lane];
#pragma unroll
        for (int t = 0; t < 8; ++t)
            if (tg == t) { tacc[t] += wf; s0t[t] += e; }
    }
#pragma unroll
    for (int t = 0; t < 8; ++t) accv[w][t][lane] = tacc[t];
    if (lane == 0) {
#pragma unroll
        for (int t = 0; t < 8; ++t) s0red[w][t] = s0t[t];
    }
    __syncthreads();
    for (int e = tid; e < 512; e += 256) {
        int t = e >> 6, d = e & 63;
        part1[((size_t)c * 32 + b) * 512 + e] =
            accv[0][t][d] + accv[1][t][d] + accv[2][t][d] + accv[3][t][d];
    }
    if (tid < 8)
        part0[((size_t)c * 32 + b) * 8 + tid] =
            s0red[0][tid] + s0red[1][tid] + s0red[2][tid] + s0red[3][tid];
}

// ---------------- K4: reduce partials + a2 head + outputs -------------------
__global__ __launch_bounds__(256)
void k_head(const float* __restrict__ part1, const float* __restrict__ part0,
            const float* __restrict__ a2w1, const float* __restrict__ a2b1,
            const float* __restrict__ a2w2, const float* __restrict__ a2b2,
            const float* __restrict__ muw, const float* __restrict__ mub,
            const float* __restrict__ lLw, const float* __restrict__ lLb,
            float* __restrict__ out)
{
    __shared__ float tf[8][64];
    __shared__ float deni[8];
    __shared__ float sc8[8];
    __shared__ float pose[64];
    int b = blockIdx.x;
    int tid = threadIdx.x;

    if (tid < 8) {
        float s = 0.f;
#pragma unroll
        for (int c = 0; c < 16; ++c) s += part0[((size_t)c * 32 + b) * 8 + tid];
        deni[tid] = 1.f / s;
    }
    __syncthreads();
    for (int e = tid; e < 512; e += 256) {
        float s = 0.f;
#pragma unroll
        for (int c = 0; c < 16; ++c) s += part1[((size_t)c * 32 + b) * 512 + e];
        tf[e >> 6][e & 63] = s * deni[e >> 6];
    }
    __syncthreads();

    {
        int t = tid >> 5, j = tid & 31;
        float acc = a2b1[j];
        for (int d = 0; d < 64; ++d) acc += tf[t][d] * a2w1[d * 32 + j];
        float hsum = fmaxf(acc, 0.f) * a2w2[j];
        hsum += __shfl_xor(hsum, 1);
        hsum += __shfl_xor(hsum, 2);
        hsum += __shfl_xor(hsum, 4);
        hsum += __shfl_xor(hsum, 8);
        hsum += __shfl_xor(hsum, 16);
        if (j == 0) sc8[t] = hsum + a2b2[0];
    }
    __syncthreads();
    if (tid < 64) {
        float smax = sc8[0];
#pragma unroll
        for (int t = 1; t < 8; ++t) smax = fmaxf(smax, sc8[t]);
        float e[8], ssum = 0.f;
#pragma unroll
        for (int t = 0; t < 8; ++t) { e[t] = exp2f((sc8[t] - smax) * LOG2E); ssum += e[t]; }
        float rinv = 1.f / ssum;
        float p = 0.f;
#pragma unroll
        for (int t = 0; t < 8; ++t) p += (e[t] * rinv) * tf[t][tid];
        pose[tid] = p;
    }
    __syncthreads();
    if (tid < 3) {
        float acc = mub[tid];
        for (int d = 0; d < 64; ++d) acc += pose[d] * muw[d * 3 + tid];
        out[b * 3 + tid] = acc;
    }
    if (tid >= 32 && tid < 38) {
        int oo = tid - 32;
        float acc = lLb[oo];
        for (int d = 0; d < 64; ++d) acc += pose[d] * lLw[d * 6 + oo];
        out[96 + b * 6 + oo] = acc;
    }
}

// ---------------------------------------------------------------------------
extern "C" void kernel_launch(void* const* d_in, const int* in_sizes, int n_in,
                              void* d_out, int out_size, void* d_ws, size_t ws_size,
                              hipStream_t stream)
{
    (void)in_sizes; (void)n_in; (void)out_size; (void)ws_size;

    const float* measurements = (const float*)d_in[0];
    const int*   mapping      = (const int*)d_in[1];
    const float* me_w1 = (const float*)d_in[2];
    const float* me_b1 = (const float*)d_in[3];
    const float* me_w2 = (const float*)d_in[4];
    const float* me_b2 = (const float*)d_in[5];
    const float* q_w   = (const float*)d_in[6];
    const float* q_b   = (const float*)d_in[7];
    const float* k_w   = (const float*)d_in[8];
    const float* k_b   = (const float*)d_in[9];
    const float* v_w   = (const float*)d_in[10];
    const float* v_b   = (const float*)d_in[11];
    const float* a1_w1 = (const float*)d_in[12];
    const float* a1_b1 = (const float*)d_in[13];
    const float* a1_w2 = (const float*)d_in[14];
    const float* a1_b2 = (const float*)d_in[15];
    const float* a2_w1 = (const float*)d_in[16];
    const float* a2_b1 = (const float*)d_in[17];
    const float* a2_w2 = (const float*)d_in[18];
    const float* a2_b2 = (const float*)d_in[19];
    const float* mu_w  = (const float*)d_in[20];
    const float* mu_b  = (const float*)d_in[21];
    const float* logL_w = (const float*)d_in[22];
    const float* logL_b = (const float*)d_in[23];

    char* ws = (char*)d_ws;
    unsigned short* wt    = (unsigned short*)(ws);                 // 32768 B
    float*          feat  = (float*)(ws + 40960);                  // 16 MB
    unsigned short* qbf   = (unsigned short*)(ws + 16818176);      // 8 MB
    unsigned short* kbf   = (unsigned short*)(ws + 25206784);      // 8 MB
    unsigned short* vt    = (unsigned short*)(ws + 33595392);      // 8 MB [b][d][m]
    float*          part1 = (float*)(ws + 42248192);               // 1 MB
    float*          part0 = (float*)(ws + 43296768);               // 16 KB
    float*          out   = (float*)d_out;

    k_prep<<<8, 256, 0, stream>>>(me_w2, q_w, k_w, v_w, wt);
    k_encode<<<1024, 256, 0, stream>>>(measurements, me_w1, me_b1, me_b2, q_b, k_b, v_b,
                                       wt, feat, qbf, kbf, vt);
    k_attn<<<512, 256, 0, stream>>>(qbf, kbf, vt, feat);
    k_a1tag<<<512, 256, 0, stream>>>(feat, mapping, a1_w1, a1_b1, a1_w2, a1_b2,
                                     part1, part0);
    k_head<<<32, 256, 0, stream>>>(part1, part0, a2_w1, a2_b1, a2_w2, a2_b2,
                                   mu_w, mu_b, logL_w, logL_b, out);
}

// Round 14
// 110.246 us; speedup vs baseline: 2.2455x; 2.2455x over previous
//
#include <hip/hip_runtime.h>
#include <hip/hip_bf16.h>
#include <cstdint>
#include <cstddef>

// ---------------------------------------------------------------------------
// UWBPoseEncoder: B=32, M=2048, T=8, H=64
// prep-weights -> encoder(h1,h2,q,k,v MFMA) -> flash-attn (round-11 proven:
// 32x32 swapped, fixed-ref exp2 softmax, XCD swizzle, 8 waves, triple buffer
// + counted vmcnt) -> fused a1+seg partials (LDS feat tile) -> head
// ---------------------------------------------------------------------------

typedef short s16x8 __attribute__((ext_vector_type(8)));
typedef float f32x4 __attribute__((ext_vector_type(4)));
typedef float f32x16 __attribute__((ext_vector_type(16)));

#define LOG2E  1.4426950408889634f
#define QSCALE 0.18033688011112042f   /* 0.125 * log2(e) */

__device__ __forceinline__ unsigned short f2bf(float f) {
    unsigned u = __builtin_bit_cast(unsigned, f);
    u += 0x7fffu + ((u >> 16) & 1u);          // RNE truncate to bf16
    return (unsigned short)(u >> 16);
}

__device__ __forceinline__ unsigned cvtpk(float lo, float hi) {
    unsigned r;
    asm("v_cvt_pk_bf16_f32 %0, %1, %2" : "=v"(r) : "v"(lo), "v"(hi));
    return r;
}

__device__ __forceinline__ float exp2_raw(float x) {
    float r;
    asm("v_exp_f32 %0, %1" : "=v"(r) : "v"(x));
    return r;
}

// swaps upper 32 lanes of a with lower 32 lanes of b
#define PLSWAP(a, b) asm("v_permlane32_swap_b32 %0, %1" : "+v"(a), "+v"(b))

// counted-vmcnt barrier: leave N newest vmem ops in flight across the barrier
#define WAITBAR(N) do { \
    asm volatile("s_waitcnt vmcnt(" #N ")\n\ts_barrier" ::: "memory"); \
    __builtin_amdgcn_sched_barrier(0); \
} while (0)

__device__ __forceinline__ void gload_lds16(const void* g, void* l) {
    __builtin_amdgcn_global_load_lds((const __attribute__((address_space(1))) void*)g,
                                     (__attribute__((address_space(3))) void*)l, 16, 0, 0);
}

#define MFMA16(a, b, c) __builtin_amdgcn_mfma_f32_16x16x32_bf16((a), (b), (c), 0, 0, 0)
#define MFMA32(a, b, c) __builtin_amdgcn_mfma_f32_32x32x16_bf16((a), (b), (c), 0, 0, 0)

// ---------------- K0: weight prep (transpose to [out][in], bf16) ------------
__global__ void k_prep(const float* __restrict__ w2, const float* __restrict__ qw,
                       const float* __restrict__ kw, const float* __restrict__ vw,
                       unsigned short* __restrict__ wt)
{
    int tid = blockIdx.x * 256 + threadIdx.x;   // 2048 threads
    for (int idx = tid; idx < 4096; idx += 2048) {
        int o = idx >> 6, i = idx & 63;
        wt[idx]         = f2bf(w2[i * 64 + o]);
        wt[4096 + idx]  = f2bf(qw[i * 64 + o] * QSCALE);
        wt[8192 + idx]  = f2bf(kw[i * 64 + o]);
        wt[12288 + idx] = f2bf(vw[i * 64 + o]);
    }
}

// ---------------- K1: encoder + QKV -----------------------------------------
__global__ __launch_bounds__(256)
void k_encode(const float* __restrict__ meas, const float* __restrict__ w1,
              const float* __restrict__ b1, const float* __restrict__ b2,
              const float* __restrict__ qb, const float* __restrict__ kb,
              const float* __restrict__ vb,
              const unsigned short* __restrict__ wt,
              float* __restrict__ feat,
              unsigned short* __restrict__ qbf, unsigned short* __restrict__ kbf,
              unsigned short* __restrict__ vt)
{
    __shared__ __align__(16) unsigned short hbuf[4][1152];   // 16 rows x 72
    int tid = threadIdx.x;
    int w = tid >> 6, lane = tid & 63;
    int g = lane >> 4, c16 = lane & 15;
    int m0 = (blockIdx.x * 4 + w) * 16;          // global row base (b*2048+m)
    int b  = m0 >> 11;
    unsigned short* hb = hbuf[w];
    int vrow = lane >> 2, vseg = lane & 3;       // vectorized-store mapping

    // ---- h1 directly in A-fragment layout ----
    float x[5];
    const float* xr = meas + (size_t)(m0 + c16) * 5;
#pragma unroll
    for (int i = 0; i < 5; ++i) x[i] = xr[i];
    s16x8 aH[2];
#pragma unroll
    for (int s = 0; s < 2; ++s) {
#pragma unroll
        for (int jj = 0; jj < 8; ++jj) {
            int j = 8 * g + jj + 32 * s;
            float acc = b1[j];
#pragma unroll
            for (int i = 0; i < 5; ++i) acc += x[i] * w1[i * 64 + j];
            aH[s][jj] = (short)f2bf(fmaxf(acc, 0.f));
        }
    }

    const f32x4 zero = {0.f, 0.f, 0.f, 0.f};
    f32x4 c[4];

    // ---- h2 = relu(h1 @ W2 + b2) ----
#pragma unroll
    for (int dt = 0; dt < 4; ++dt) {
        c[dt] = zero;
#pragma unroll
        for (int s = 0; s < 2; ++s) {
            s16x8 bf = *(const s16x8*)(wt + (c16 + 16 * dt) * 64 + 32 * s + 8 * g);
            c[dt] = MFMA16(aH[s], bf, c[dt]);
        }
    }
#pragma unroll
    for (int dt = 0; dt < 4; ++dt) {
        int d = c16 + 16 * dt;
        float bias = b2[d];
#pragma unroll
        for (int r = 0; r < 4; ++r) {
            float v = fmaxf(c[dt][r] + bias, 0.f);
            feat[(size_t)(m0 + 4 * g + r) * 64 + d] = v;
            hb[(4 * g + r) * 72 + d] = f2bf(v);
        }
    }
    s16x8 aF[2];
#pragma unroll
    for (int s = 0; s < 2; ++s)
        aF[s] = *(const s16x8*)(hb + c16 * 72 + 32 * s + 8 * g);

    auto gemmW = [&](const unsigned short* wmat, f32x4* cc) {
#pragma unroll
        for (int dt = 0; dt < 4; ++dt) {
            cc[dt] = zero;
#pragma unroll
            for (int s = 0; s < 2; ++s) {
                s16x8 bf = *(const s16x8*)(wmat + (c16 + 16 * dt) * 64 + 32 * s + 8 * g);
                cc[dt] = MFMA16(aF[s], bf, cc[dt]);
            }
        }
    };
    // write C-tile (plus bias) to wave-private LDS, then 2x16B coalesced store
    auto storeV = [&](const float* bias4, unsigned short* dstbase) {
#pragma unroll
        for (int dt = 0; dt < 4; ++dt) {
            int d = c16 + 16 * dt;
#pragma unroll
            for (int r = 0; r < 4; ++r)
                hb[(4 * g + r) * 72 + d] = f2bf(c[dt][r] + bias4[dt]);
        }
        s16x8 o0 = *(const s16x8*)(hb + vrow * 72 + vseg * 16);
        s16x8 o1 = *(const s16x8*)(hb + vrow * 72 + vseg * 16 + 8);
        unsigned short* dst = dstbase + (size_t)(m0 + vrow) * 64 + vseg * 16;
        *(s16x8*)dst = o0;
        *(s16x8*)(dst + 8) = o1;
    };

    float bias4[4];
    // ---- q (pre-scaled) ----
    gemmW(wt + 4096, c);
#pragma unroll
    for (int dt = 0; dt < 4; ++dt) bias4[dt] = qb[c16 + 16 * dt] * QSCALE;
    storeV(bias4, qbf);
    // ---- k ----
    gemmW(wt + 8192, c);
#pragma unroll
    for (int dt = 0; dt < 4; ++dt) bias4[dt] = kb[c16 + 16 * dt];
    storeV(bias4, kbf);
    // ---- v: compute, transpose through LDS, store vt[b][d][m] ----
    gemmW(wt + 12288, c);
#pragma unroll
    for (int dt = 0; dt < 4; ++dt) {
        int d = c16 + 16 * dt;
        float bias = vb[d];
#pragma unroll
        for (int r = 0; r < 4; ++r)
            hb[(4 * g + r) * 72 + d] = f2bf(c[dt][r] + bias);
    }
    unsigned short tvv[16];
#pragma unroll
    for (int mr = 0; mr < 16; ++mr) tvv[mr] = hb[mr * 72 + lane];   // column d=lane
    s16x8 v0, v1;
#pragma unroll
    for (int e2 = 0; e2 < 8; ++e2) { v0[e2] = (short)tvv[e2]; v1[e2] = (short)tvv[8 + e2]; }
    unsigned short* dst = vt + ((size_t)b * 64 + lane) * 2048 + (m0 & 2047);
    *(s16x8*)dst = v0;
    *(s16x8*)(dst + 8) = v1;
}

// ---------------- K2: flash attention (round-11 proven config) --------------
// 512 blocks x 512 thr (8 waves), triple-buffered staging, counted vmcnt(2),
// XCD swizzle, fixed-reference exp2 softmax, split-K pairs.
__global__ __launch_bounds__(512, 4)
void k_attn(const unsigned short* __restrict__ qbf, const unsigned short* __restrict__ kbf,
            const unsigned short* __restrict__ vt, float* __restrict__ feat)
{
    __shared__ __align__(16) char smem[49152];
    // staging: K[3][64][64]bf16 @0 (3x8KB), V[3][64][64]bf16 @24576 (3x8KB)
    // merge (after loop): Om[4][64][36]f32 @0 (36864B), Ml[4][32]f32 @36864

    int tid = threadIdx.x;
    int w_ = tid >> 6, lane = tid & 63;
    int h = lane >> 5, c32 = lane & 31;
    int jhalf = w_ & 1, tile = w_ >> 1;
    int bid = (int)blockIdx.x;
    bid = (bid & 7) * 64 + (bid >> 3);           // XCD-aware swizzle (bijective)
    int b = bid >> 4;
    int q0g = (bid & 15) * 128 + tile * 32;
    size_t rowbase = (size_t)b * 2048;

    const unsigned short* kbf_b = kbf + rowbase * 64;
    const unsigned short* vt_b  = vt + (size_t)b * 64 * 2048;

    s16x8 qf[4];
    {
        const unsigned short* qp = qbf + (rowbase + q0g + c32) * 64 + 8 * h;
#pragma unroll
        for (int st = 0; st < 4; ++st)
            qf[st] = *(const s16x8*)(qp + 16 * st);
    }

    f32x16 zero16;
#pragma unroll
    for (int i = 0; i < 16; ++i) zero16[i] = 0.f;

    f32x16 o[2];
#pragma unroll
    for (int dt = 0; dt < 2; ++dt)
#pragma unroll
        for (int i = 0; i < 16; ++i) o[dt][i] = 0.f;
    float ll = 0.f;

    int srow = 8 * w_ + (lane >> 3);
    int scol = (lane & 7) ^ (srow & 7);
    const unsigned short* gk0 = kbf_b + (size_t)srow * 64 + scol * 8;
    const unsigned short* gv0 = vt_b + (size_t)srow * 2048 + scol * 8;

    auto stage = [&](int kt, int buf) {
        gload_lds16(gk0 + (size_t)kt * 4096, smem + buf * 8192 + w_ * 1024);
        gload_lds16(gv0 + kt * 64, smem + 24576 + buf * 8192 + w_ * 1024);
    };

    int swz = c32 & 7;
    int krow = 32 * jhalf + c32;

    auto compute = [&](int buf) {
        const char* Kb = smem + buf * 8192;
        const char* Vb = smem + 24576 + buf * 8192;

        s16x8 kf[4], vf[2][2];
#pragma unroll
        for (int st = 0; st < 4; ++st)
            kf[st] = *(const s16x8*)(Kb + krow * 128 + (((2 * st + h) ^ swz) * 16));
#pragma unroll
        for (int ks = 0; ks < 2; ++ks)
#pragma unroll
            for (int dt = 0; dt < 2; ++dt)
                vf[ks][dt] = *(const s16x8*)(Vb + (32 * dt + c32) * 128 +
                                             (((4 * jhalf + 2 * ks + h) ^ swz) * 16));

        __builtin_amdgcn_s_setprio(1);
        f32x16 sc = MFMA32(kf[0], qf[0], zero16);
#pragma unroll
        for (int st = 1; st < 4; ++st)
            sc = MFMA32(kf[st], qf[st], sc);
        __builtin_amdgcn_s_setprio(0);

        float p[16];
#pragma unroll
        for (int i = 0; i < 16; ++i) p[i] = exp2_raw(sc[i]);

        float s;
        {
            float a0 = p[0] + p[1],  a1 = p[2] + p[3],  a2 = p[4] + p[5],  a3 = p[6] + p[7];
            float a4 = p[8] + p[9],  a5 = p[10] + p[11], a6 = p[12] + p[13], a7 = p[14] + p[15];
            float b0 = a0 + a1, b1 = a2 + a3, b2 = a4 + a5, b3 = a6 + a7;
            s = (b0 + b1) + (b2 + b3);
        }
        {
            float s1 = s, s2 = s;
            PLSWAP(s1, s2);
            s = s1 + s2;
        }
        ll += s;

        unsigned u[8];
#pragma unroll
        for (int k2 = 0; k2 < 8; ++k2) u[k2] = cvtpk(p[2 * k2], p[2 * k2 + 1]);

        __builtin_amdgcn_s_setprio(1);
#pragma unroll
        for (int ks = 0; ks < 2; ++ks) {
            unsigned a0 = u[4 * ks + 0], b0 = u[4 * ks + 2];
            unsigned a1 = u[4 * ks + 1], b1 = u[4 * ks + 3];
            PLSWAP(a0, b0);
            PLSWAP(a1, b1);
            union { unsigned uu[4]; s16x8 v; } pa;
            pa.uu[0] = a0; pa.uu[1] = a1; pa.uu[2] = b0; pa.uu[3] = b1;
#pragma unroll
            for (int dt = 0; dt < 2; ++dt)
                o[dt] = MFMA32(pa.v, vf[ks][dt], o[dt]);
        }
        __builtin_amdgcn_s_setprio(0);
    };

    // prologue: 2 tiles in flight; wait only the oldest (tile 0)
    stage(0, 0);
    stage(1, 1);
    WAITBAR(2);

#pragma unroll 3
    for (int kt = 0; kt < 30; ++kt) {
        stage(kt + 2, (kt + 2) % 3);
        compute(kt % 3);
        WAITBAR(2);     // retire tile kt+1's loads; tile kt+2's stay in flight
    }
    compute(0);          // tile 30 (30%3==0)
    WAITBAR(0);          // retire tile 31's loads
    compute(1);          // tile 31 (31%3==1)
    __syncthreads();     // LDS reuse for merge

    // ---- merge split-K pairs (w, w^1) and write feat += O/l ----
    float* Om = (float*)smem;                 // [4][64][36]
    float* Ml = (float*)(smem + 36864);       // [4][32]
    if (jhalf) {
#pragma unroll
        for (int dt = 0; dt < 2; ++dt)
#pragma unroll
            for (int rg = 0; rg < 4; ++rg) {
                f32x4 vv;
#pragma unroll
                for (int r = 0; r < 4; ++r) vv[r] = o[dt][4 * rg + r];
                *(f32x4*)&Om[(tile * 64 + 32 * dt + c32) * 36 + 8 * rg + 4 * h] = vv;
            }
        if (h == 0) Ml[tile * 32 + c32] = ll;
    }
    __syncthreads();
    if (!jhalf) {
        float l1 = Ml[tile * 32 + c32];
        float f = 1.f / (ll + l1);
        float fr[16];
#pragma unroll
        for (int r = 0; r < 16; ++r) {
            int qrow = (r & 3) + 8 * (r >> 2) + 4 * h;
            fr[r] = __shfl(f, qrow);
        }
#pragma unroll
        for (int dt = 0; dt < 2; ++dt)
#pragma unroll
            for (int rg = 0; rg < 4; ++rg) {
                f32x4 pv = *(const f32x4*)&Om[(tile * 64 + 32 * dt + c32) * 36 + 8 * rg + 4 * h];
#pragma unroll
                for (int r = 0; r < 4; ++r) {
                    int rr = 4 * rg + r;
                    int qrow = r + 8 * rg + 4 * h;
                    size_t fi = (rowbase + q0g + qrow) * 64 + 32 * dt + c32;
                    feat[fi] += (o[dt][rr] + pv[r]) * fr[rr];
                }
            }
    }
}

// ---------------- K3: fused a1 MLP + unnormalized tag partials --------------
// 512 blocks = 32 batches x 16 chunks of 128 rows. feat tile staged in LDS
// during phase A; phase B reads LDS instead of re-reading 16MB from HBM.
__global__ __launch_bounds__(256)
void k_a1tag(const float* __restrict__ feat, const int* __restrict__ map,
             const float* __restrict__ a1w1, const float* __restrict__ b1,
             const float* __restrict__ w2, const float* __restrict__ b2,
             float* __restrict__ part1, float* __restrict__ part0)
{
    __shared__ float fls[128][68];      // feat tile (pad 68: b128 writes spread)
    __shared__ float psum[128][33];
    __shared__ float es[128];
    __shared__ float accv[4][8][64];
    __shared__ float s0red[4][8];

    int b = blockIdx.x >> 4;
    int c = blockIdx.x & 15;
    int tid = threadIdx.x, lane = tid & 63, w = tid >> 6;
    int m0 = c * 128;
    const int* mp = map + b * 2048 + m0;
    const float* fbase = feat + ((size_t)b * 2048 + m0) * 64;

    // phase A: a1 for 128 rows, k-split across thread halves (kh = 0/1);
    // feat tile copied to LDS on the way through.
    {
        int r = tid & 127, kh = tid >> 7;
        const f32x4* fr4 = (const f32x4*)(fbase + (size_t)r * 64 + kh * 32);
        float acc[32];
#pragma unroll
        for (int j = 0; j < 32; ++j) acc[j] = kh ? 0.f : b1[j];
#pragma unroll
        for (int kc = 0; kc < 8; ++kc) {
            f32x4 fv = fr4[kc];
            *(f32x4*)&fls[r][kh * 32 + kc * 4] = fv;
#pragma unroll
            for (int ki = 0; ki < 4; ++ki) {
                const float* wr = a1w1 + (kh * 32 + kc * 4 + ki) * 32;   // [k][j]
#pragma unroll
                for (int j = 0; j < 32; ++j)
                    acc[j] = fmaf(fv[ki], wr[j], acc[j]);
            }
        }
        if (kh) {
#pragma unroll
            for (int j = 0; j < 32; ++j) psum[r][j] = acc[j];
        }
        __syncthreads();
        if (!kh) {
            float s = b2[0];
#pragma unroll
            for (int j = 0; j < 32; ++j)
                s += fmaxf(acc[j] + psum[r][j], 0.f) * w2[j];
            es[r] = exp2_raw(s * LOG2E);
        }
    }
    __syncthreads();

    // phase B: unnormalized weighted-feat partials per tag (feat from LDS)
    float tacc[8], s0t[8];
#pragma unroll
    for (int t = 0; t < 8; ++t) { tacc[t] = 0.f; s0t[t] = 0.f; }
    for (int mi = w; mi < 128; mi += 4) {
        int tg = mp[mi];
        float e = es[mi];
        float wf = e * fls[mi][lane];
#pragma unroll
        for (int t = 0; t < 8; ++t)
            if (tg == t) { tacc[t] += wf; s0t[t] += e; }
    }
#pragma unroll
    for (int t = 0; t < 8; ++t) accv[w][t][lane] = tacc[t];
    if (lane == 0) {
#pragma unroll
        for (int t = 0; t < 8; ++t) s0red[w][t] = s0t[t];
    }
    __syncthreads();
    for (int e = tid; e < 512; e += 256) {
        int t = e >> 6, d = e & 63;
        part1[((size_t)c * 32 + b) * 512 + e] =
            accv[0][t][d] + accv[1][t][d] + accv[2][t][d] + accv[3][t][d];
    }
    if (tid < 8)
        part0[((size_t)c * 32 + b) * 8 + tid] =
            s0red[0][tid] + s0red[1][tid] + s0red[2][tid] + s0red[3][tid];
}

// ---------------- K4: reduce partials + a2 head + outputs -------------------
__global__ __launch_bounds__(256)
void k_head(const float* __restrict__ part1, const float* __restrict__ part0,
            const float* __restrict__ a2w1, const float* __restrict__ a2b1,
            const float* __restrict__ a2w2, const float* __restrict__ a2b2,
            const float* __restrict__ muw, const float* __restrict__ mub,
            const float* __restrict__ lLw, const float* __restrict__ lLb,
            float* __restrict__ out)
{
    __shared__ float tf[8][64];
    __shared__ float deni[8];
    __shared__ float sc8[8];
    __shared__ float pose[64];
    int b = blockIdx.x;
    int tid = threadIdx.x;

    if (tid < 8) {
        float s = 0.f;
#pragma unroll
        for (int c = 0; c < 16; ++c) s += part0[((size_t)c * 32 + b) * 8 + tid];
        deni[tid] = 1.f / s;
    }
    __syncthreads();
    for (int e = tid; e < 512; e += 256) {
        float s = 0.f;
#pragma unroll
        for (int c = 0; c < 16; ++c) s += part1[((size_t)c * 32 + b) * 512 + e];
        tf[e >> 6][e & 63] = s * deni[e >> 6];
    }
    __syncthreads();

    {
        int t = tid >> 5, j = tid & 31;
        float acc = a2b1[j];
        for (int d = 0; d < 64; ++d) acc += tf[t][d] * a2w1[d * 32 + j];
        float hsum = fmaxf(acc, 0.f) * a2w2[j];
        hsum += __shfl_xor(hsum, 1);
        hsum += __shfl_xor(hsum, 2);
        hsum += __shfl_xor(hsum, 4);
        hsum += __shfl_xor(hsum, 8);
        hsum += __shfl_xor(hsum, 16);
        if (j == 0) sc8[t] = hsum + a2b2[0];
    }
    __syncthreads();
    if (tid < 64) {
        float smax = sc8[0];
#pragma unroll
        for (int t = 1; t < 8; ++t) smax = fmaxf(smax, sc8[t]);
        float e[8], ssum = 0.f;
#pragma unroll
        for (int t = 0; t < 8; ++t) { e[t] = exp2f((sc8[t] - smax) * LOG2E); ssum += e[t]; }
        float rinv = 1.f / ssum;
        float p = 0.f;
#pragma unroll
        for (int t = 0; t < 8; ++t) p += (e[t] * rinv) * tf[t][tid];
        pose[tid] = p;
    }
    __syncthreads();
    if (tid < 3) {
        float acc = mub[tid];
        for (int d = 0; d < 64; ++d) acc += pose[d] * muw[d * 3 + tid];
        out[b * 3 + tid] = acc;
    }
    if (tid >= 32 && tid < 38) {
        int oo = tid - 32;
        float acc = lLb[oo];
        for (int d = 0; d < 64; ++d) acc += pose[d] * lLw[d * 6 + oo];
        out[96 + b * 6 + oo] = acc;
    }
}

// ---------------------------------------------------------------------------
extern "C" void kernel_launch(void* const* d_in, const int* in_sizes, int n_in,
                              void* d_out, int out_size, void* d_ws, size_t ws_size,
                              hipStream_t stream)
{
    (void)in_sizes; (void)n_in; (void)out_size; (void)ws_size;

    const float* measurements = (const float*)d_in[0];
    const int*   mapping      = (const int*)d_in[1];
    const float* me_w1 = (const float*)d_in[2];
    const float* me_b1 = (const float*)d_in[3];
    const float* me_w2 = (const float*)d_in[4];
    const float* me_b2 = (const float*)d_in[5];
    const float* q_w   = (const float*)d_in[6];
    const float* q_b   = (const float*)d_in[7];
    const float* k_w   = (const float*)d_in[8];
    const float* k_b   = (const float*)d_in[9];
    const float* v_w   = (const float*)d_in[10];
    const float* v_b   = (const float*)d_in[11];
    const float* a1_w1 = (const float*)d_in[12];
    const float* a1_b1 = (const float*)d_in[13];
    const float* a1_w2 = (const float*)d_in[14];
    const float* a1_b2 = (const float*)d_in[15];
    const float* a2_w1 = (const float*)d_in[16];
    const float* a2_b1 = (const float*)d_in[17];
    const float* a2_w2 = (const float*)d_in[18];
    const float* a2_b2 = (const float*)d_in[19];
    const float* mu_w  = (const float*)d_in[20];
    const float* mu_b  = (const float*)d_in[21];
    const float* logL_w = (const float*)d_in[22];
    const float* logL_b = (const float*)d_in[23];

    char* ws = (char*)d_ws;
    unsigned short* wt    = (unsigned short*)(ws);                 // 32768 B
    float*          feat  = (float*)(ws + 40960);                  // 16 MB
    unsigned short* qbf   = (unsigned short*)(ws + 16818176);      // 8 MB
    unsigned short* kbf   = (unsigned short*)(ws + 25206784);      // 8 MB
    unsigned short* vt    = (unsigned short*)(ws + 33595392);      // 8 MB [b][d][m]
    float*          part1 = (float*)(ws + 42248192);               // 1 MB
    float*          part0 = (float*)(ws + 43296768);               // 16 KB
    float*          out   = (float*)d_out;

    k_prep<<<8, 256, 0, stream>>>(me_w2, q_w, k_w, v_w, wt);
    k_encode<<<1024, 256, 0, stream>>>(measurements, me_w1, me_b1, me_b2, q_b, k_b, v_b,
                                       wt, feat, qbf, kbf, vt);
    k_attn<<<512, 512, 0, stream>>>(qbf, kbf, vt, feat);
    k_a1tag<<<512, 256, 0, stream>>>(feat, mapping, a1_w1, a1_b1, a1_w2, a1_b2,
                                     part1, part0);
    k_head<<<32, 256, 0, stream>>>(part1, part0, a2_w1, a2_b1, a2_w2, a2_b2,
                                   mu_w, mu_b, logL_w, logL_b, out);
}

// Round 15
// 108.826 us; speedup vs baseline: 2.2749x; 1.0131x over previous
//
#include <hip/hip_runtime.h>
#include <hip/hip_bf16.h>
#include <cstdint>
#include <cstddef>

// ---------------------------------------------------------------------------
// UWBPoseEncoder: B=32, M=2048, T=8, H=64
// prep-weights -> encoder(h1,h2,q,k,v MFMA) -> flash-attn (round-11 K-loop,
// fused epilogue: split-K merge in LDS + residual + a1 MLP + unnormalized
// tag partials; feat_total never hits HBM) -> head
// ---------------------------------------------------------------------------

typedef short s16x8 __attribute__((ext_vector_type(8)));
typedef float f32x4 __attribute__((ext_vector_type(4)));
typedef float f32x16 __attribute__((ext_vector_type(16)));

#define LOG2E  1.4426950408889634f
#define QSCALE 0.18033688011112042f   /* 0.125 * log2(e) */

__device__ __forceinline__ unsigned short f2bf(float f) {
    unsigned u = __builtin_bit_cast(unsigned, f);
    u += 0x7fffu + ((u >> 16) & 1u);          // RNE truncate to bf16
    return (unsigned short)(u >> 16);
}

__device__ __forceinline__ unsigned cvtpk(float lo, float hi) {
    unsigned r;
    asm("v_cvt_pk_bf16_f32 %0, %1, %2" : "=v"(r) : "v"(lo), "v"(hi));
    return r;
}

__device__ __forceinline__ float exp2_raw(float x) {
    float r;
    asm("v_exp_f32 %0, %1" : "=v"(r) : "v"(x));
    return r;
}

// swaps upper 32 lanes of a with lower 32 lanes of b
#define PLSWAP(a, b) asm("v_permlane32_swap_b32 %0, %1" : "+v"(a), "+v"(b))

// counted-vmcnt barrier: leave N newest vmem ops in flight across the barrier
#define WAITBAR(N) do { \
    asm volatile("s_waitcnt vmcnt(" #N ")\n\ts_barrier" ::: "memory"); \
    __builtin_amdgcn_sched_barrier(0); \
} while (0)

__device__ __forceinline__ void gload_lds16(const void* g, void* l) {
    __builtin_amdgcn_global_load_lds((const __attribute__((address_space(1))) void*)g,
                                     (__attribute__((address_space(3))) void*)l, 16, 0, 0);
}

#define MFMA16(a, b, c) __builtin_amdgcn_mfma_f32_16x16x32_bf16((a), (b), (c), 0, 0, 0)
#define MFMA32(a, b, c) __builtin_amdgcn_mfma_f32_32x32x16_bf16((a), (b), (c), 0, 0, 0)

// ---------------- K0: weight prep (transpose to [out][in], bf16) ------------
__global__ void k_prep(const float* __restrict__ w2, const float* __restrict__ qw,
                       const float* __restrict__ kw, const float* __restrict__ vw,
                       unsigned short* __restrict__ wt)
{
    int tid = blockIdx.x * 256 + threadIdx.x;   // 2048 threads
    for (int idx = tid; idx < 4096; idx += 2048) {
        int o = idx >> 6, i = idx & 63;
        wt[idx]         = f2bf(w2[i * 64 + o]);
        wt[4096 + idx]  = f2bf(qw[i * 64 + o] * QSCALE);
        wt[8192 + idx]  = f2bf(kw[i * 64 + o]);
        wt[12288 + idx] = f2bf(vw[i * 64 + o]);
    }
}

// ---------------- K1: encoder + QKV -----------------------------------------
__global__ __launch_bounds__(256)
void k_encode(const float* __restrict__ meas, const float* __restrict__ w1,
              const float* __restrict__ b1, const float* __restrict__ b2,
              const float* __restrict__ qb, const float* __restrict__ kb,
              const float* __restrict__ vb,
              const unsigned short* __restrict__ wt,
              float* __restrict__ feat,
              unsigned short* __restrict__ qbf, unsigned short* __restrict__ kbf,
              unsigned short* __restrict__ vt)
{
    __shared__ __align__(16) unsigned short hbuf[4][1152];   // 16 rows x 72
    int tid = threadIdx.x;
    int w = tid >> 6, lane = tid & 63;
    int g = lane >> 4, c16 = lane & 15;
    int m0 = (blockIdx.x * 4 + w) * 16;          // global row base (b*2048+m)
    int b  = m0 >> 11;
    unsigned short* hb = hbuf[w];
    int vrow = lane >> 2, vseg = lane & 3;       // vectorized-store mapping

    // ---- h1 directly in A-fragment layout ----
    float x[5];
    const float* xr = meas + (size_t)(m0 + c16) * 5;
#pragma unroll
    for (int i = 0; i < 5; ++i) x[i] = xr[i];
    s16x8 aH[2];
#pragma unroll
    for (int s = 0; s < 2; ++s) {
#pragma unroll
        for (int jj = 0; jj < 8; ++jj) {
            int j = 8 * g + jj + 32 * s;
            float acc = b1[j];
#pragma unroll
            for (int i = 0; i < 5; ++i) acc += x[i] * w1[i * 64 + j];
            aH[s][jj] = (short)f2bf(fmaxf(acc, 0.f));
        }
    }

    const f32x4 zero = {0.f, 0.f, 0.f, 0.f};
    f32x4 c[4];

    // ---- h2 = relu(h1 @ W2 + b2) ----
#pragma unroll
    for (int dt = 0; dt < 4; ++dt) {
        c[dt] = zero;
#pragma unroll
        for (int s = 0; s < 2; ++s) {
            s16x8 bf = *(const s16x8*)(wt + (c16 + 16 * dt) * 64 + 32 * s + 8 * g);
            c[dt] = MFMA16(aH[s], bf, c[dt]);
        }
    }
#pragma unroll
    for (int dt = 0; dt < 4; ++dt) {
        int d = c16 + 16 * dt;
        float bias = b2[d];
#pragma unroll
        for (int r = 0; r < 4; ++r) {
            float v = fmaxf(c[dt][r] + bias, 0.f);
            feat[(size_t)(m0 + 4 * g + r) * 64 + d] = v;
            hb[(4 * g + r) * 72 + d] = f2bf(v);
        }
    }
    s16x8 aF[2];
#pragma unroll
    for (int s = 0; s < 2; ++s)
        aF[s] = *(const s16x8*)(hb + c16 * 72 + 32 * s + 8 * g);

    auto gemmW = [&](const unsigned short* wmat, f32x4* cc) {
#pragma unroll
        for (int dt = 0; dt < 4; ++dt) {
            cc[dt] = zero;
#pragma unroll
            for (int s = 0; s < 2; ++s) {
                s16x8 bf = *(const s16x8*)(wmat + (c16 + 16 * dt) * 64 + 32 * s + 8 * g);
                cc[dt] = MFMA16(aF[s], bf, cc[dt]);
            }
        }
    };
    // write C-tile (plus bias) to wave-private LDS, then 2x16B coalesced store
    auto storeV = [&](const float* bias4, unsigned short* dstbase) {
#pragma unroll
        for (int dt = 0; dt < 4; ++dt) {
            int d = c16 + 16 * dt;
#pragma unroll
            for (int r = 0; r < 4; ++r)
                hb[(4 * g + r) * 72 + d] = f2bf(c[dt][r] + bias4[dt]);
        }
        s16x8 o0 = *(const s16x8*)(hb + vrow * 72 + vseg * 16);
        s16x8 o1 = *(const s16x8*)(hb + vrow * 72 + vseg * 16 + 8);
        unsigned short* dst = dstbase + (size_t)(m0 + vrow) * 64 + vseg * 16;
        *(s16x8*)dst = o0;
        *(s16x8*)(dst + 8) = o1;
    };

    float bias4[4];
    // ---- q (pre-scaled) ----
    gemmW(wt + 4096, c);
#pragma unroll
    for (int dt = 0; dt < 4; ++dt) bias4[dt] = qb[c16 + 16 * dt] * QSCALE;
    storeV(bias4, qbf);
    // ---- k ----
    gemmW(wt + 8192, c);
#pragma unroll
    for (int dt = 0; dt < 4; ++dt) bias4[dt] = kb[c16 + 16 * dt];
    storeV(bias4, kbf);
    // ---- v: compute, transpose through LDS, store vt[b][d][m] ----
    gemmW(wt + 12288, c);
#pragma unroll
    for (int dt = 0; dt < 4; ++dt) {
        int d = c16 + 16 * dt;
        float bias = vb[d];
#pragma unroll
        for (int r = 0; r < 4; ++r)
            hb[(4 * g + r) * 72 + d] = f2bf(c[dt][r] + bias);
    }
    unsigned short tvv[16];
#pragma unroll
    for (int mr = 0; mr < 16; ++mr) tvv[mr] = hb[mr * 72 + lane];   // column d=lane
    s16x8 v0, v1;
#pragma unroll
    for (int e2 = 0; e2 < 8; ++e2) { v0[e2] = (short)tvv[e2]; v1[e2] = (short)tvv[8 + e2]; }
    unsigned short* dst = vt + ((size_t)b * 64 + lane) * 2048 + (m0 & 2047);
    *(s16x8*)dst = v0;
    *(s16x8*)(dst + 8) = v1;
}

// ---------------- K2: flash attention + fused a1/tag epilogue ---------------
// 512 blocks x 512 thr (8 waves). K-loop identical to round-11 (proven 46us).
// Epilogue: split-K merge into LDS fls[128][68], + residual feat_enc, then
// a1 MLP (4 lanes/row) and unnormalized tag partials -> part1/part0.
__global__ __launch_bounds__(512, 4)
void k_attn(const unsigned short* __restrict__ qbf, const unsigned short* __restrict__ kbf,
            const unsigned short* __restrict__ vt, const float* __restrict__ feat,
            const int* __restrict__ map,
            const float* __restrict__ a1w1, const float* __restrict__ a1b1,
            const float* __restrict__ a1w2, const float* __restrict__ a1b2,
            float* __restrict__ part1, float* __restrict__ part0)
{
    __shared__ __align__(16) char smem[52480];
    // loop:     K[3][64][64]bf16 @0 (24576), V[3][64][64]bf16 @24576 (24576)
    // epilogue: fls[128][68]f32 @0 (34816), Ml[4][32] @34816 (512),
    //           es[128] @35328 (512), accv[8][8][64] @35840 (16384),
    //           s0r[8][8] @52224 (256)  -> total 52480

    int tid = threadIdx.x;
    int w_ = tid >> 6, lane = tid & 63;
    int h = lane >> 5, c32 = lane & 31;
    int jhalf = w_ & 1, tile = w_ >> 1;
    int bid = (int)blockIdx.x;
    bid = (bid & 7) * 64 + (bid >> 3);           // XCD-aware swizzle (bijective)
    int b = bid >> 4;
    int chunk = bid & 15;
    int q0g = chunk * 128 + tile * 32;
    size_t rowbase = (size_t)b * 2048;

    const unsigned short* kbf_b = kbf + rowbase * 64;
    const unsigned short* vt_b  = vt + (size_t)b * 64 * 2048;

    s16x8 qf[4];
    {
        const unsigned short* qp = qbf + (rowbase + q0g + c32) * 64 + 8 * h;
#pragma unroll
        for (int st = 0; st < 4; ++st)
            qf[st] = *(const s16x8*)(qp + 16 * st);
    }

    f32x16 zero16;
#pragma unroll
    for (int i = 0; i < 16; ++i) zero16[i] = 0.f;

    f32x16 o[2];
#pragma unroll
    for (int dt = 0; dt < 2; ++dt)
#pragma unroll
        for (int i = 0; i < 16; ++i) o[dt][i] = 0.f;
    float ll = 0.f;

    int srow = 8 * w_ + (lane >> 3);
    int scol = (lane & 7) ^ (srow & 7);
    const unsigned short* gk0 = kbf_b + (size_t)srow * 64 + scol * 8;
    const unsigned short* gv0 = vt_b + (size_t)srow * 2048 + scol * 8;

    auto stage = [&](int kt, int buf) {
        gload_lds16(gk0 + (size_t)kt * 4096, smem + buf * 8192 + w_ * 1024);
        gload_lds16(gv0 + kt * 64, smem + 24576 + buf * 8192 + w_ * 1024);
    };

    int swz = c32 & 7;
    int krow = 32 * jhalf + c32;

    auto compute = [&](int buf) {
        const char* Kb = smem + buf * 8192;
        const char* Vb = smem + 24576 + buf * 8192;

        s16x8 kf[4], vf[2][2];
#pragma unroll
        for (int st = 0; st < 4; ++st)
            kf[st] = *(const s16x8*)(Kb + krow * 128 + (((2 * st + h) ^ swz) * 16));
#pragma unroll
        for (int ks = 0; ks < 2; ++ks)
#pragma unroll
            for (int dt = 0; dt < 2; ++dt)
                vf[ks][dt] = *(const s16x8*)(Vb + (32 * dt + c32) * 128 +
                                             (((4 * jhalf + 2 * ks + h) ^ swz) * 16));

        __builtin_amdgcn_s_setprio(1);
        f32x16 sc = MFMA32(kf[0], qf[0], zero16);
#pragma unroll
        for (int st = 1; st < 4; ++st)
            sc = MFMA32(kf[st], qf[st], sc);
        __builtin_amdgcn_s_setprio(0);

        float p[16];
#pragma unroll
        for (int i = 0; i < 16; ++i) p[i] = exp2_raw(sc[i]);

        float s;
        {
            float a0 = p[0] + p[1],  a1 = p[2] + p[3],  a2 = p[4] + p[5],  a3 = p[6] + p[7];
            float a4 = p[8] + p[9],  a5 = p[10] + p[11], a6 = p[12] + p[13], a7 = p[14] + p[15];
            float b0 = a0 + a1, b1 = a2 + a3, b2 = a4 + a5, b3 = a6 + a7;
            s = (b0 + b1) + (b2 + b3);
        }
        {
            float s1 = s, s2 = s;
            PLSWAP(s1, s2);
            s = s1 + s2;
        }
        ll += s;

        unsigned u[8];
#pragma unroll
        for (int k2 = 0; k2 < 8; ++k2) u[k2] = cvtpk(p[2 * k2], p[2 * k2 + 1]);

        __builtin_amdgcn_s_setprio(1);
#pragma unroll
        for (int ks = 0; ks < 2; ++ks) {
            unsigned a0 = u[4 * ks + 0], b0 = u[4 * ks + 2];
            unsigned a1 = u[4 * ks + 1], b1 = u[4 * ks + 3];
            PLSWAP(a0, b0);
            PLSWAP(a1, b1);
            union { unsigned uu[4]; s16x8 v; } pa;
            pa.uu[0] = a0; pa.uu[1] = a1; pa.uu[2] = b0; pa.uu[3] = b1;
#pragma unroll
            for (int dt = 0; dt < 2; ++dt)
                o[dt] = MFMA32(pa.v, vf[ks][dt], o[dt]);
        }
        __builtin_amdgcn_s_setprio(0);
    };

    // prologue: 2 tiles in flight; wait only the oldest (tile 0)
    stage(0, 0);
    stage(1, 1);
    WAITBAR(2);

#pragma unroll 3
    for (int kt = 0; kt < 30; ++kt) {
        stage(kt + 2, (kt + 2) % 3);
        compute(kt % 3);
        WAITBAR(2);     // retire tile kt+1's loads; tile kt+2's stay in flight
    }
    compute(0);          // tile 30 (30%3==0)
    WAITBAR(0);          // retire tile 31's loads
    compute(1);          // tile 31 (31%3==1)
    __syncthreads();     // LDS reuse for epilogue

    // ---- fused epilogue ----
    float* fls = (float*)smem;                 // [128][68]
    float* Ml  = (float*)(smem + 34816);       // [4][32]
    float* es  = (float*)(smem + 35328);       // [128]
    float* accv = (float*)(smem + 35840);      // [8][8][64]
    float* s0r  = (float*)(smem + 52224);      // [8][8]

    // merge step 1: jhalf waves publish partial O and l
    if (jhalf) {
#pragma unroll
        for (int dt = 0; dt < 2; ++dt)
#pragma unroll
            for (int rg = 0; rg < 4; ++rg)
#pragma unroll
                for (int r = 0; r < 4; ++r) {
                    int row = tile * 32 + r + 8 * rg + 4 * h;
                    fls[row * 68 + 32 * dt + c32] = o[dt][4 * rg + r];
                }
        if (h == 0) Ml[tile * 32 + c32] = ll;
    }
    __syncthreads();
    // merge step 2: !jhalf combines, normalizes, adds residual, stores feat_total
    if (!jhalf) {
        float l1 = Ml[tile * 32 + c32];
        float f = 1.f / (ll + l1);
        float fr[16];
#pragma unroll
        for (int r = 0; r < 16; ++r) {
            int qrow = (r & 3) + 8 * (r >> 2) + 4 * h;
            fr[r] = __shfl(f, qrow);
        }
#pragma unroll
        for (int dt = 0; dt < 2; ++dt)
#pragma unroll
            for (int rg = 0; rg < 4; ++rg)
#pragma unroll
                for (int r = 0; r < 4; ++r) {
                    int rr = 4 * rg + r;
                    int row = tile * 32 + r + 8 * rg + 4 * h;
                    size_t fi = (rowbase + chunk * 128 + row) * 64 + 32 * dt + c32;
                    float val = (o[dt][rr] + fls[row * 68 + 32 * dt + c32]) * fr[rr]
                              + feat[fi];
                    fls[row * 68 + 32 * dt + c32] = val;
                }
    }
    __syncthreads();

    // phase A: a1 per row (4 lanes/row, 8 hidden units each), es = exp2(a1*log2e)
    {
        int row = tid >> 2, jq = tid & 3;
        const float* frw = &fls[row * 68];
        float acc[8];
#pragma unroll
        for (int j8 = 0; j8 < 8; ++j8) acc[j8] = 0.f;
#pragma unroll
        for (int kc = 0; kc < 16; ++kc) {
            f32x4 fv = *(const f32x4*)&frw[kc * 4];
#pragma unroll
            for (int ki = 0; ki < 4; ++ki) {
                const float* wr = a1w1 + (kc * 4 + ki) * 32 + jq * 8;
#pragma unroll
                for (int j8 = 0; j8 < 8; ++j8)
                    acc[j8] = fmaf(fv[ki], wr[j8], acc[j8]);
            }
        }
        float s = 0.f;
#pragma unroll
        for (int j8 = 0; j8 < 8; ++j8)
            s += fmaxf(acc[j8] + a1b1[jq * 8 + j8], 0.f) * a1w2[jq * 8 + j8];
        s += __shfl_xor(s, 1);
        s += __shfl_xor(s, 2);
        if (jq == 0) es[row] = exp2_raw((s + a1b2[0]) * LOG2E);
    }
    __syncthreads();

    // phase B: unnormalized weighted-feat partials per tag
    {
        const int* mp = map + b * 2048 + chunk * 128;
        float tacc[8], s0t[8];
#pragma unroll
        for (int t = 0; t < 8; ++t) { tacc[t] = 0.f; s0t[t] = 0.f; }
        for (int mi = w_; mi < 128; mi += 8) {
            int tg = mp[mi];
            float e = es[mi];
            float wf = e * fls[mi * 68 + lane];
#pragma unroll
            for (int t = 0; t < 8; ++t)
                if (tg == t) { tacc[t] += wf; s0t[t] += e; }
        }
#pragma unroll
        for (int t = 0; t < 8; ++t) accv[(w_ * 8 + t) * 64 + lane] = tacc[t];
        if (lane == 0) {
#pragma unroll
            for (int t = 0; t < 8; ++t) s0r[w_ * 8 + t] = s0t[t];
        }
    }
    __syncthreads();
    {
        int e = tid;            // 512 threads -> one element each
        float sum = 0.f;
#pragma unroll
        for (int w8 = 0; w8 < 8; ++w8) sum += accv[w8 * 512 + e];
        part1[((size_t)chunk * 32 + b) * 512 + e] = sum;
        if (tid < 8) {
            float s = 0.f;
#pragma unroll
            for (int w8 = 0; w8 < 8; ++w8) s += s0r[w8 * 8 + tid];
            part0[((size_t)chunk * 32 + b) * 8 + tid] = s;
        }
    }
}

// ---------------- K3: reduce partials + a2 head + outputs -------------------
__global__ __launch_bounds__(256)
void k_head(const float* __restrict__ part1, const float* __restrict__ part0,
            const float* __restrict__ a2w1, const float* __restrict__ a2b1,
            const float* __restrict__ a2w2, const float* __restrict__ a2b2,
            const float* __restrict__ muw, const float* __restrict__ mub,
            const float* __restrict__ lLw, const float* __restrict__ lLb,
            float* __restrict__ out)
{
    __shared__ float tf[8][64];
    __shared__ float deni[8];
    __shared__ float sc8[8];
    __shared__ float pose[64];
    int b = blockIdx.x;
    int tid = threadIdx.x;

    if (tid < 8) {
        float s = 0.f;
#pragma unroll
        for (int c = 0; c < 16; ++c) s += part0[((size_t)c * 32 + b) * 8 + tid];
        deni[tid] = 1.f / s;
    }
    __syncthreads();
    for (int e = tid; e < 512; e += 256) {
        float s = 0.f;
#pragma unroll
        for (int c = 0; c < 16; ++c) s += part1[((size_t)c * 32 + b) * 512 + e];
        tf[e >> 6][e & 63] = s * deni[e >> 6];
    }
    __syncthreads();

    {
        int t = tid >> 5, j = tid & 31;
        float acc = a2b1[j];
        for (int d = 0; d < 64; ++d) acc += tf[t][d] * a2w1[d * 32 + j];
        float hsum = fmaxf(acc, 0.f) * a2w2[j];
        hsum += __shfl_xor(hsum, 1);
        hsum += __shfl_xor(hsum, 2);
        hsum += __shfl_xor(hsum, 4);
        hsum += __shfl_xor(hsum, 8);
        hsum += __shfl_xor(hsum, 16);
        if (j == 0) sc8[t] = hsum + a2b2[0];
    }
    __syncthreads();
    if (tid < 64) {
        float smax = sc8[0];
#pragma unroll
        for (int t = 1; t < 8; ++t) smax = fmaxf(smax, sc8[t]);
        float e[8], ssum = 0.f;
#pragma unroll
        for (int t = 0; t < 8; ++t) { e[t] = exp2f((sc8[t] - smax) * LOG2E); ssum += e[t]; }
        float rinv = 1.f / ssum;
        float p = 0.f;
#pragma unroll
        for (int t = 0; t < 8; ++t) p += (e[t] * rinv) * tf[t][tid];
        pose[tid] = p;
    }
    __syncthreads();
    if (tid < 3) {
        float acc = mub[tid];
        for (int d = 0; d < 64; ++d) acc += pose[d] * muw[d * 3 + tid];
        out[b * 3 + tid] = acc;
    }
    if (tid >= 32 && tid < 38) {
        int oo = tid - 32;
        float acc = lLb[oo];
        for (int d = 0; d < 64; ++d) acc += pose[d] * lLw[d * 6 + oo];
        out[96 + b * 6 + oo] = acc;
    }
}

// ---------------------------------------------------------------------------
extern "C" void kernel_launch(void* const* d_in, const int* in_sizes, int n_in,
                              void* d_out, int out_size, void* d_ws, size_t ws_size,
                              hipStream_t stream)
{
    (void)in_sizes; (void)n_in; (void)out_size; (void)ws_size;

    const float* measurements = (const float*)d_in[0];
    const int*   mapping      = (const int*)d_in[1];
    const float* me_w1 = (const float*)d_in[2];
    const float* me_b1 = (const float*)d_in[3];
    const float* me_w2 = (const float*)d_in[4];
    const float* me_b2 = (const float*)d_in[5];
    const float* q_w   = (const float*)d_in[6];
    const float* q_b   = (const float*)d_in[7];
    const float* k_w   = (const float*)d_in[8];
    const float* k_b   = (const float*)d_in[9];
    const float* v_w   = (const float*)d_in[10];
    const float* v_b   = (const float*)d_in[11];
    const float* a1_w1 = (const float*)d_in[12];
    const float* a1_b1 = (const float*)d_in[13];
    const float* a1_w2 = (const float*)d_in[14];
    const float* a1_b2 = (const float*)d_in[15];
    const float* a2_w1 = (const float*)d_in[16];
    const float* a2_b1 = (const float*)d_in[17];
    const float* a2_w2 = (const float*)d_in[18];
    const float* a2_b2 = (const float*)d_in[19];
    const float* mu_w  = (const float*)d_in[20];
    const float* mu_b  = (const float*)d_in[21];
    const float* logL_w = (const float*)d_in[22];
    const float* logL_b = (const float*)d_in[23];

    char* ws = (char*)d_ws;
    unsigned short* wt    = (unsigned short*)(ws);                 // 32768 B
    float*          feat  = (float*)(ws + 40960);                  // 16 MB
    unsigned short* qbf   = (unsigned short*)(ws + 16818176);      // 8 MB
    unsigned short* kbf   = (unsigned short*)(ws + 25206784);      // 8 MB
    unsigned short* vt    = (unsigned short*)(ws + 33595392);      // 8 MB [b][d][m]
    float*          part1 = (float*)(ws + 42248192);               // 1 MB
    float*          part0 = (float*)(ws + 43296768);               // 16 KB
    float*          out   = (float*)d_out;

    k_prep<<<8, 256, 0, stream>>>(me_w2, q_w, k_w, v_w, wt);
    k_encode<<<1024, 256, 0, stream>>>(measurements, me_w1, me_b1, me_b2, q_b, k_b, v_b,
                                       wt, feat, qbf, kbf, vt);
    k_attn<<<512, 512, 0, stream>>>(qbf, kbf, vt, feat, mapping,
                                    a1_w1, a1_b1, a1_w2, a1_b2, part1, part0);
    k_head<<<32, 256, 0, stream>>>(part1, part0, a2_w1, a2_b1, a2_w2, a2_b2,
                                   mu_w, mu_b, logL_w, logL_b, out);
}

// Round 16
// 108.395 us; speedup vs baseline: 2.2839x; 1.0040x over previous
//
#include <hip/hip_runtime.h>
#include <hip/hip_bf16.h>
#include <cstdint>
#include <cstddef>

// ---------------------------------------------------------------------------
// UWBPoseEncoder: B=32, M=2048, T=8, H=64
// prep-weights -> encoder(h1,h2,q,k,v MFMA) -> flash-attn (round-11 K-loop,
// fused epilogue: split-K merge in LDS + residual + a1 MLP (wave-uniform
// scalar-cached weights) + unnormalized tag partials) -> head
// ---------------------------------------------------------------------------

typedef short s16x8 __attribute__((ext_vector_type(8)));
typedef float f32x4 __attribute__((ext_vector_type(4)));
typedef float f32x16 __attribute__((ext_vector_type(16)));

#define LOG2E  1.4426950408889634f
#define QSCALE 0.18033688011112042f   /* 0.125 * log2(e) */

__device__ __forceinline__ unsigned short f2bf(float f) {
    unsigned u = __builtin_bit_cast(unsigned, f);
    u += 0x7fffu + ((u >> 16) & 1u);          // RNE truncate to bf16
    return (unsigned short)(u >> 16);
}

__device__ __forceinline__ unsigned cvtpk(float lo, float hi) {
    unsigned r;
    asm("v_cvt_pk_bf16_f32 %0, %1, %2" : "=v"(r) : "v"(lo), "v"(hi));
    return r;
}

__device__ __forceinline__ float exp2_raw(float x) {
    float r;
    asm("v_exp_f32 %0, %1" : "=v"(r) : "v"(x));
    return r;
}

// swaps upper 32 lanes of a with lower 32 lanes of b
#define PLSWAP(a, b) asm("v_permlane32_swap_b32 %0, %1" : "+v"(a), "+v"(b))

// counted-vmcnt barrier: leave N newest vmem ops in flight across the barrier
#define WAITBAR(N) do { \
    asm volatile("s_waitcnt vmcnt(" #N ")\n\ts_barrier" ::: "memory"); \
    __builtin_amdgcn_sched_barrier(0); \
} while (0)

__device__ __forceinline__ void gload_lds16(const void* g, void* l) {
    __builtin_amdgcn_global_load_lds((const __attribute__((address_space(1))) void*)g,
                                     (__attribute__((address_space(3))) void*)l, 16, 0, 0);
}

#define MFMA16(a, b, c) __builtin_amdgcn_mfma_f32_16x16x32_bf16((a), (b), (c), 0, 0, 0)
#define MFMA32(a, b, c) __builtin_amdgcn_mfma_f32_32x32x16_bf16((a), (b), (c), 0, 0, 0)

// ---------------- K0: weight prep (transpose to [out][in], bf16) ------------
__global__ void k_prep(const float* __restrict__ w2, const float* __restrict__ qw,
                       const float* __restrict__ kw, const float* __restrict__ vw,
                       unsigned short* __restrict__ wt)
{
    int tid = blockIdx.x * 256 + threadIdx.x;   // 2048 threads
    for (int idx = tid; idx < 4096; idx += 2048) {
        int o = idx >> 6, i = idx & 63;
        wt[idx]         = f2bf(w2[i * 64 + o]);
        wt[4096 + idx]  = f2bf(qw[i * 64 + o] * QSCALE);
        wt[8192 + idx]  = f2bf(kw[i * 64 + o]);
        wt[12288 + idx] = f2bf(vw[i * 64 + o]);
    }
}

// ---------------- K1: encoder + QKV -----------------------------------------
__global__ __launch_bounds__(256)
void k_encode(const float* __restrict__ meas, const float* __restrict__ w1,
              const float* __restrict__ b1, const float* __restrict__ b2,
              const float* __restrict__ qb, const float* __restrict__ kb,
              const float* __restrict__ vb,
              const unsigned short* __restrict__ wt,
              float* __restrict__ feat,
              unsigned short* __restrict__ qbf, unsigned short* __restrict__ kbf,
              unsigned short* __restrict__ vt)
{
    __shared__ __align__(16) unsigned short hbuf[4][1152];   // 16 rows x 72
    int tid = threadIdx.x;
    int w = tid >> 6, lane = tid & 63;
    int g = lane >> 4, c16 = lane & 15;
    int m0 = (blockIdx.x * 4 + w) * 16;          // global row base (b*2048+m)
    int b  = m0 >> 11;
    unsigned short* hb = hbuf[w];
    int vrow = lane >> 2, vseg = lane & 3;       // vectorized-store mapping

    // ---- h1 directly in A-fragment layout ----
    float x[5];
    const float* xr = meas + (size_t)(m0 + c16) * 5;
#pragma unroll
    for (int i = 0; i < 5; ++i) x[i] = xr[i];
    s16x8 aH[2];
#pragma unroll
    for (int s = 0; s < 2; ++s) {
#pragma unroll
        for (int jj = 0; jj < 8; ++jj) {
            int j = 8 * g + jj + 32 * s;
            float acc = b1[j];
#pragma unroll
            for (int i = 0; i < 5; ++i) acc += x[i] * w1[i * 64 + j];
            aH[s][jj] = (short)f2bf(fmaxf(acc, 0.f));
        }
    }

    const f32x4 zero = {0.f, 0.f, 0.f, 0.f};
    f32x4 c[4];

    // ---- h2 = relu(h1 @ W2 + b2) ----
#pragma unroll
    for (int dt = 0; dt < 4; ++dt) {
        c[dt] = zero;
#pragma unroll
        for (int s = 0; s < 2; ++s) {
            s16x8 bf = *(const s16x8*)(wt + (c16 + 16 * dt) * 64 + 32 * s + 8 * g);
            c[dt] = MFMA16(aH[s], bf, c[dt]);
        }
    }
#pragma unroll
    for (int dt = 0; dt < 4; ++dt) {
        int d = c16 + 16 * dt;
        float bias = b2[d];
#pragma unroll
        for (int r = 0; r < 4; ++r) {
            float v = fmaxf(c[dt][r] + bias, 0.f);
            feat[(size_t)(m0 + 4 * g + r) * 64 + d] = v;
            hb[(4 * g + r) * 72 + d] = f2bf(v);
        }
    }
    s16x8 aF[2];
#pragma unroll
    for (int s = 0; s < 2; ++s)
        aF[s] = *(const s16x8*)(hb + c16 * 72 + 32 * s + 8 * g);

    auto gemmW = [&](const unsigned short* wmat, f32x4* cc) {
#pragma unroll
        for (int dt = 0; dt < 4; ++dt) {
            cc[dt] = zero;
#pragma unroll
            for (int s = 0; s < 2; ++s) {
                s16x8 bf = *(const s16x8*)(wmat + (c16 + 16 * dt) * 64 + 32 * s + 8 * g);
                cc[dt] = MFMA16(aF[s], bf, cc[dt]);
            }
        }
    };
    // write C-tile (plus bias) to wave-private LDS, then 2x16B coalesced store
    auto storeV = [&](const float* bias4, unsigned short* dstbase) {
#pragma unroll
        for (int dt = 0; dt < 4; ++dt) {
            int d = c16 + 16 * dt;
#pragma unroll
            for (int r = 0; r < 4; ++r)
                hb[(4 * g + r) * 72 + d] = f2bf(c[dt][r] + bias4[dt]);
        }
        s16x8 o0 = *(const s16x8*)(hb + vrow * 72 + vseg * 16);
        s16x8 o1 = *(const s16x8*)(hb + vrow * 72 + vseg * 16 + 8);
        unsigned short* dst = dstbase + (size_t)(m0 + vrow) * 64 + vseg * 16;
        *(s16x8*)dst = o0;
        *(s16x8*)(dst + 8) = o1;
    };

    float bias4[4];
    // ---- q (pre-scaled) ----
    gemmW(wt + 4096, c);
#pragma unroll
    for (int dt = 0; dt < 4; ++dt) bias4[dt] = qb[c16 + 16 * dt] * QSCALE;
    storeV(bias4, qbf);
    // ---- k ----
    gemmW(wt + 8192, c);
#pragma unroll
    for (int dt = 0; dt < 4; ++dt) bias4[dt] = kb[c16 + 16 * dt];
    storeV(bias4, kbf);
    // ---- v: compute, transpose through LDS, store vt[b][d][m] ----
    gemmW(wt + 12288, c);
#pragma unroll
    for (int dt = 0; dt < 4; ++dt) {
        int d = c16 + 16 * dt;
        float bias = vb[d];
#pragma unroll
        for (int r = 0; r < 4; ++r)
            hb[(4 * g + r) * 72 + d] = f2bf(c[dt][r] + bias);
    }
    unsigned short tvv[16];
#pragma unroll
    for (int mr = 0; mr < 16; ++mr) tvv[mr] = hb[mr * 72 + lane];   // column d=lane
    s16x8 v0, v1;
#pragma unroll
    for (int e2 = 0; e2 < 8; ++e2) { v0[e2] = (short)tvv[e2]; v1[e2] = (short)tvv[8 + e2]; }
    unsigned short* dst = vt + ((size_t)b * 64 + lane) * 2048 + (m0 & 2047);
    *(s16x8*)dst = v0;
    *(s16x8*)(dst + 8) = v1;
}

// ---------------- K2: flash attention + fused a1/tag epilogue ---------------
// 512 blocks x 512 thr (8 waves). K-loop identical to round-11 (proven 46us).
// Epilogue: split-K merge into LDS fls[128][68] + residual (preloaded), a1
// MLP with WAVE-UNIFORM weight indices (scalar cache), tag partials.
__global__ __launch_bounds__(512, 4)
void k_attn(const unsigned short* __restrict__ qbf, const unsigned short* __restrict__ kbf,
            const unsigned short* __restrict__ vt, const float* __restrict__ feat,
            const int* __restrict__ map,
            const float* __restrict__ a1w1, const float* __restrict__ a1b1,
            const float* __restrict__ a1w2, const float* __restrict__ a1b2,
            float* __restrict__ part1, float* __restrict__ part0)
{
    __shared__ __align__(16) char smem[52480];
    // loop:     K[3][64][64]bf16 @0 (24576), V[3][64][64]bf16 @24576 (24576)
    // epilogue: fls[128][68]f32 @0 (34816), Ml[4][32] @34816 (512),
    //           es[128] @35328 (512), scratch @35840:
    //             phase A: sred[4][128] (2048)
    //             phase B: accv[8][8][64] (16384) + s0r[8][8] @52224 (256)

    int tid = threadIdx.x;
    int w_ = tid >> 6, lane = tid & 63;
    int h = lane >> 5, c32 = lane & 31;
    int jhalf = w_ & 1, tile = w_ >> 1;
    int bid = (int)blockIdx.x;
    bid = (bid & 7) * 64 + (bid >> 3);           // XCD-aware swizzle (bijective)
    int b = bid >> 4;
    int chunk = bid & 15;
    int q0g = chunk * 128 + tile * 32;
    size_t rowbase = (size_t)b * 2048;

    const unsigned short* kbf_b = kbf + rowbase * 64;
    const unsigned short* vt_b  = vt + (size_t)b * 64 * 2048;

    s16x8 qf[4];
    {
        const unsigned short* qp = qbf + (rowbase + q0g + c32) * 64 + 8 * h;
#pragma unroll
        for (int st = 0; st < 4; ++st)
            qf[st] = *(const s16x8*)(qp + 16 * st);
    }

    f32x16 zero16;
#pragma unroll
    for (int i = 0; i < 16; ++i) zero16[i] = 0.f;

    f32x16 o[2];
#pragma unroll
    for (int dt = 0; dt < 2; ++dt)
#pragma unroll
        for (int i = 0; i < 16; ++i) o[dt][i] = 0.f;
    float ll = 0.f;

    int srow = 8 * w_ + (lane >> 3);
    int scol = (lane & 7) ^ (srow & 7);
    const unsigned short* gk0 = kbf_b + (size_t)srow * 64 + scol * 8;
    const unsigned short* gv0 = vt_b + (size_t)srow * 2048 + scol * 8;

    auto stage = [&](int kt, int buf) {
        gload_lds16(gk0 + (size_t)kt * 4096, smem + buf * 8192 + w_ * 1024);
        gload_lds16(gv0 + kt * 64, smem + 24576 + buf * 8192 + w_ * 1024);
    };

    int swz = c32 & 7;
    int krow = 32 * jhalf + c32;

    auto compute = [&](int buf) {
        const char* Kb = smem + buf * 8192;
        const char* Vb = smem + 24576 + buf * 8192;

        s16x8 kf[4], vf[2][2];
#pragma unroll
        for (int st = 0; st < 4; ++st)
            kf[st] = *(const s16x8*)(Kb + krow * 128 + (((2 * st + h) ^ swz) * 16));
#pragma unroll
        for (int ks = 0; ks < 2; ++ks)
#pragma unroll
            for (int dt = 0; dt < 2; ++dt)
                vf[ks][dt] = *(const s16x8*)(Vb + (32 * dt + c32) * 128 +
                                             (((4 * jhalf + 2 * ks + h) ^ swz) * 16));

        __builtin_amdgcn_s_setprio(1);
        f32x16 sc = MFMA32(kf[0], qf[0], zero16);
#pragma unroll
        for (int st = 1; st < 4; ++st)
            sc = MFMA32(kf[st], qf[st], sc);
        __builtin_amdgcn_s_setprio(0);

        float p[16];
#pragma unroll
        for (int i = 0; i < 16; ++i) p[i] = exp2_raw(sc[i]);

        float s;
        {
            float a0 = p[0] + p[1],  a1 = p[2] + p[3],  a2 = p[4] + p[5],  a3 = p[6] + p[7];
            float a4 = p[8] + p[9],  a5 = p[10] + p[11], a6 = p[12] + p[13], a7 = p[14] + p[15];
            float b0 = a0 + a1, b1 = a2 + a3, b2 = a4 + a5, b3 = a6 + a7;
            s = (b0 + b1) + (b2 + b3);
        }
        {
            float s1 = s, s2 = s;
            PLSWAP(s1, s2);
            s = s1 + s2;
        }
        ll += s;

        unsigned u[8];
#pragma unroll
        for (int k2 = 0; k2 < 8; ++k2) u[k2] = cvtpk(p[2 * k2], p[2 * k2 + 1]);

        __builtin_amdgcn_s_setprio(1);
#pragma unroll
        for (int ks = 0; ks < 2; ++ks) {
            unsigned a0 = u[4 * ks + 0], b0 = u[4 * ks + 2];
            unsigned a1 = u[4 * ks + 1], b1 = u[4 * ks + 3];
            PLSWAP(a0, b0);
            PLSWAP(a1, b1);
            union { unsigned uu[4]; s16x8 v; } pa;
            pa.uu[0] = a0; pa.uu[1] = a1; pa.uu[2] = b0; pa.uu[3] = b1;
#pragma unroll
            for (int dt = 0; dt < 2; ++dt)
                o[dt] = MFMA32(pa.v, vf[ks][dt], o[dt]);
        }
        __builtin_amdgcn_s_setprio(0);
    };

    // prologue: 2 tiles in flight; wait only the oldest (tile 0)
    stage(0, 0);
    stage(1, 1);
    WAITBAR(2);

#pragma unroll 3
    for (int kt = 0; kt < 30; ++kt) {
        stage(kt + 2, (kt + 2) % 3);
        compute(kt % 3);
        WAITBAR(2);     // retire tile kt+1's loads; tile kt+2's stay in flight
    }
    compute(0);          // tile 30 (30%3==0)
    WAITBAR(0);          // retire tile 31's loads
    compute(1);          // tile 31 (31%3==1)

    // residual preload: issue global loads BEFORE the merge barriers so the
    // L2/L3 latency hides under merge step 1.
    float resid[2][16];
    if (!jhalf) {
#pragma unroll
        for (int dt = 0; dt < 2; ++dt)
#pragma unroll
            for (int rg = 0; rg < 4; ++rg)
#pragma unroll
                for (int r = 0; r < 4; ++r) {
                    int row = tile * 32 + r + 8 * rg + 4 * h;
                    size_t fi = (rowbase + chunk * 128 + row) * 64 + 32 * dt + c32;
                    resid[dt][4 * rg + r] = feat[fi];
                }
    }
    __syncthreads();     // LDS reuse for epilogue

    // ---- fused epilogue ----
    float* fls = (float*)smem;                 // [128][68]
    float* Ml  = (float*)(smem + 34816);       // [4][32]
    float* es  = (float*)(smem + 35328);       // [128]
    float* sred = (float*)(smem + 35840);      // [4][128]   (phase A)
    float* accv = (float*)(smem + 35840);      // [8][8][64] (phase B)
    float* s0r  = (float*)(smem + 52224);      // [8][8]     (phase B)

    // merge step 1: jhalf waves publish partial O and l
    if (jhalf) {
#pragma unroll
        for (int dt = 0; dt < 2; ++dt)
#pragma unroll
            for (int rg = 0; rg < 4; ++rg)
#pragma unroll
                for (int r = 0; r < 4; ++r) {
                    int row = tile * 32 + r + 8 * rg + 4 * h;
                    fls[row * 68 + 32 * dt + c32] = o[dt][4 * rg + r];
                }
        if (h == 0) Ml[tile * 32 + c32] = ll;
    }
    __syncthreads();
    // merge step 2: !jhalf combines, normalizes, adds residual -> feat_total in LDS
    if (!jhalf) {
        float l1 = Ml[tile * 32 + c32];
        float f = 1.f / (ll + l1);
        float fr[16];
#pragma unroll
        for (int r = 0; r < 16; ++r) {
            int qrow = (r & 3) + 8 * (r >> 2) + 4 * h;
            fr[r] = __shfl(f, qrow);
        }
#pragma unroll
        for (int dt = 0; dt < 2; ++dt)
#pragma unroll
            for (int rg = 0; rg < 4; ++rg)
#pragma unroll
                for (int r = 0; r < 4; ++r) {
                    int rr = 4 * rg + r;
                    int row = tile * 32 + r + 8 * rg + 4 * h;
                    float val = (o[dt][rr] + fls[row * 68 + 32 * dt + c32]) * fr[rr]
                              + resid[dt][rr];
                    fls[row * 68 + 32 * dt + c32] = val;
                }
    }
    __syncthreads();

    // phase A: a1 per row. Wave-uniform hidden-quarter jqw = w_&3 -> weight
    // addresses are wave-uniform (s_load, scalar cache). Rows: lane + 64*(w_>>2).
    {
        int jqw = w_ & 3;
        int row = (w_ >> 2) * 64 + lane;
        const float* wbase = a1w1 + jqw * 8;            // wave-uniform
        const float* frw = &fls[row * 68];
        float acc[8];
#pragma unroll
        for (int j8 = 0; j8 < 8; ++j8) acc[j8] = 0.f;
#pragma unroll
        for (int kc = 0; kc < 16; ++kc) {
            f32x4 fv = *(const f32x4*)&frw[kc * 4];
#pragma unroll
            for (int ki = 0; ki < 4; ++ki) {
                const float* wr = wbase + (kc * 4 + ki) * 32;   // wave-uniform
#pragma unroll
                for (int j8 = 0; j8 < 8; ++j8)
                    acc[j8] = fmaf(fv[ki], wr[j8], acc[j8]);
            }
        }
        float s = 0.f;
#pragma unroll
        for (int j8 = 0; j8 < 8; ++j8)
            s += fmaxf(acc[j8] + a1b1[jqw * 8 + j8], 0.f) * a1w2[jqw * 8 + j8];
        sred[jqw * 128 + row] = s;
    }
    __syncthreads();
    if (tid < 128) {
        float a1v = sred[tid] + sred[128 + tid] + sred[256 + tid] + sred[384 + tid];
        es[tid] = exp2_raw((a1v + a1b2[0]) * LOG2E);
    }
    __syncthreads();

    // phase B: unnormalized weighted-feat partials per tag
    {
        const int* mp = map + b * 2048 + chunk * 128;
        float tacc[8], s0t[8];
#pragma unroll
        for (int t = 0; t < 8; ++t) { tacc[t] = 0.f; s0t[t] = 0.f; }
        for (int mi = w_; mi < 128; mi += 8) {
            int tg = mp[mi];
            float e = es[mi];
            float wf = e * fls[mi * 68 + lane];
#pragma unroll
            for (int t = 0; t < 8; ++t)
                if (tg == t) { tacc[t] += wf; s0t[t] += e; }
        }
#pragma unroll
        for (int t = 0; t < 8; ++t) accv[(w_ * 8 + t) * 64 + lane] = tacc[t];
        if (lane == 0) {
#pragma unroll
            for (int t = 0; t < 8; ++t) s0r[w_ * 8 + t] = s0t[t];
        }
    }
    __syncthreads();
    {
        int e = tid;            // 512 threads -> one element each
        float sum = 0.f;
#pragma unroll
        for (int w8 = 0; w8 < 8; ++w8) sum += accv[w8 * 512 + e];
        part1[((size_t)chunk * 32 + b) * 512 + e] = sum;
        if (tid < 8) {
            float s = 0.f;
#pragma unroll
            for (int w8 = 0; w8 < 8; ++w8) s += s0r[w8 * 8 + tid];
            part0[((size_t)chunk * 32 + b) * 8 + tid] = s;
        }
    }
}

// ---------------- K3: reduce partials + a2 head + outputs -------------------
__global__ __launch_bounds__(256)
void k_head(const float* __restrict__ part1, const float* __restrict__ part0,
            const float* __restrict__ a2w1, const float* __restrict__ a2b1,
            const float* __restrict__ a2w2, const float* __restrict__ a2b2,
            const float* __restrict__ muw, const float* __restrict__ mub,
            const float* __restrict__ lLw, const float* __restrict__ lLb,
            float* __restrict__ out)
{
    __shared__ float tf[8][64];
    __shared__ float deni[8];
    __shared__ float sc8[8];
    __shared__ float pose[64];
    int b = blockIdx.x;
    int tid = threadIdx.x;

    if (tid < 8) {
        float s = 0.f;
#pragma unroll
        for (int c = 0; c < 16; ++c) s += part0[((size_t)c * 32 + b) * 8 + tid];
        deni[tid] = 1.f / s;
    }
    __syncthreads();
    for (int e = tid; e < 512; e += 256) {
        float s = 0.f;
#pragma unroll
        for (int c = 0; c < 16; ++c) s += part1[((size_t)c * 32 + b) * 512 + e];
        tf[e >> 6][e & 63] = s * deni[e >> 6];
    }
    __syncthreads();

    {
        int t = tid >> 5, j = tid & 31;
        float acc = a2b1[j];
        for (int d = 0; d < 64; ++d) acc += tf[t][d] * a2w1[d * 32 + j];
        float hsum = fmaxf(acc, 0.f) * a2w2[j];
        hsum += __shfl_xor(hsum, 1);
        hsum += __shfl_xor(hsum, 2);
        hsum += __shfl_xor(hsum, 4);
        hsum += __shfl_xor(hsum, 8);
        hsum += __shfl_xor(hsum, 16);
        if (j == 0) sc8[t] = hsum + a2b2[0];
    }
    __syncthreads();
    if (tid < 64) {
        float smax = sc8[0];
#pragma unroll
        for (int t = 1; t < 8; ++t) smax = fmaxf(smax, sc8[t]);
        float e[8], ssum = 0.f;
#pragma unroll
        for (int t = 0; t < 8; ++t) { e[t] = exp2f((sc8[t] - smax) * LOG2E); ssum += e[t]; }
        float rinv = 1.f / ssum;
        float p = 0.f;
#pragma unroll
        for (int t = 0; t < 8; ++t) p += (e[t] * rinv) * tf[t][tid];
        pose[tid] = p;
    }
    __syncthreads();
    if (tid < 3) {
        float acc = mub[tid];
        for (int d = 0; d < 64; ++d) acc += pose[d] * muw[d * 3 + tid];
        out[b * 3 + tid] = acc;
    }
    if (tid >= 32 && tid < 38) {
        int oo = tid - 32;
        float acc = lLb[oo];
        for (int d = 0; d < 64; ++d) acc += pose[d] * lLw[d * 6 + oo];
        out[96 + b * 6 + oo] = acc;
    }
}

// ---------------------------------------------------------------------------
extern "C" void kernel_launch(void* const* d_in, const int* in_sizes, int n_in,
                              void* d_out, int out_size, void* d_ws, size_t ws_size,
                              hipStream_t stream)
{
    (void)in_sizes; (void)n_in; (void)out_size; (void)ws_size;

    const float* measurements = (const float*)d_in[0];
    const int*   mapping      = (const int*)d_in[1];
    const float* me_w1 = (const float*)d_in[2];
    const float* me_b1 = (const float*)d_in[3];
    const float* me_w2 = (const float*)d_in[4];
    const float* me_b2 = (const float*)d_in[5];
    const float* q_w   = (const float*)d_in[6];
    const float* q_b   = (const float*)d_in[7];
    const float* k_w   = (const float*)d_in[8];
    const float* k_b   = (const float*)d_in[9];
    const float* v_w   = (const float*)d_in[10];
    const float* v_b   = (const float*)d_in[11];
    const float* a1_w1 = (const float*)d_in[12];
    const float* a1_b1 = (const float*)d_in[13];
    const float* a1_w2 = (const float*)d_in[14];
    const float* a1_b2 = (const float*)d_in[15];
    const float* a2_w1 = (const float*)d_in[16];
    const float* a2_b1 = (const float*)d_in[17];
    const float* a2_w2 = (const float*)d_in[18];
    const float* a2_b2 = (const float*)d_in[19];
    const float* mu_w  = (const float*)d_in[20];
    const float* mu_b  = (const float*)d_in[21];
    const float* logL_w = (const float*)d_in[22];
    const float* logL_b = (const float*)d_in[23];

    char* ws = (char*)d_ws;
    unsigned short* wt    = (unsigned short*)(ws);                 // 32768 B
    float*          feat  = (float*)(ws + 40960);                  // 16 MB
    unsigned short* qbf   = (unsigned short*)(ws + 16818176);      // 8 MB
    unsigned short* kbf   = (unsigned short*)(ws + 25206784);      // 8 MB
    unsigned short* vt    = (unsigned short*)(ws + 33595392);      // 8 MB [b][d][m]
    float*          part1 = (float*)(ws + 42248192);               // 1 MB
    float*          part0 = (float*)(ws + 43296768);               // 16 KB
    float*          out   = (float*)d_out;

    k_prep<<<8, 256, 0, stream>>>(me_w2, q_w, k_w, v_w, wt);
    k_encode<<<1024, 256, 0, stream>>>(measurements, me_w1, me_b1, me_b2, q_b, k_b, v_b,
                                       wt, feat, qbf, kbf, vt);
    k_attn<<<512, 512, 0, stream>>>(qbf, kbf, vt, feat, mapping,
                                    a1_w1, a1_b1, a1_w2, a1_b2, part1, part0);
    k_head<<<32, 256, 0, stream>>>(part1, part0, a2_w1, a2_b1, a2_w2, a2_b2,
                                   mu_w, mu_b, logL_w, logL_b, out);
}

// Round 17
// 107.860 us; speedup vs baseline: 2.2952x; 1.0050x over previous
//
#include <hip/hip_runtime.h>
#include <hip/hip_bf16.h>
#include <cstdint>
#include <cstddef>

// ---------------------------------------------------------------------------
// UWBPoseEncoder: B=32, M=2048, T=8, H=64
// prep-weights -> encoder(h1,h2,q,k,v MFMA) -> flash-attn (round-11 K-loop,
// fused epilogue: split-K merge in LDS + residual + a1 MLP (wave-uniform
// scalar-cached weights) + unnormalized tag partials) -> head
// ---------------------------------------------------------------------------

typedef short s16x8 __attribute__((ext_vector_type(8)));
typedef float f32x4 __attribute__((ext_vector_type(4)));
typedef float f32x16 __attribute__((ext_vector_type(16)));

#define LOG2E  1.4426950408889634f
#define QSCALE 0.18033688011112042f   /* 0.125 * log2(e) */

__device__ __forceinline__ unsigned short f2bf(float f) {
    unsigned u = __builtin_bit_cast(unsigned, f);
    u += 0x7fffu + ((u >> 16) & 1u);          // RNE truncate to bf16
    return (unsigned short)(u >> 16);
}

__device__ __forceinline__ unsigned cvtpk(float lo, float hi) {
    unsigned r;
    asm("v_cvt_pk_bf16_f32 %0, %1, %2" : "=v"(r) : "v"(lo), "v"(hi));
    return r;
}

__device__ __forceinline__ float exp2_raw(float x) {
    float r;
    asm("v_exp_f32 %0, %1" : "=v"(r) : "v"(x));
    return r;
}

// swaps upper 32 lanes of a with lower 32 lanes of b
#define PLSWAP(a, b) asm("v_permlane32_swap_b32 %0, %1" : "+v"(a), "+v"(b))

// counted-vmcnt barrier: leave N newest vmem ops in flight across the barrier
#define WAITBAR(N) do { \
    asm volatile("s_waitcnt vmcnt(" #N ")\n\ts_barrier" ::: "memory"); \
    __builtin_amdgcn_sched_barrier(0); \
} while (0)

__device__ __forceinline__ void gload_lds16(const void* g, void* l) {
    __builtin_amdgcn_global_load_lds((const __attribute__((address_space(1))) void*)g,
                                     (__attribute__((address_space(3))) void*)l, 16, 0, 0);
}

#define MFMA16(a, b, c) __builtin_amdgcn_mfma_f32_16x16x32_bf16((a), (b), (c), 0, 0, 0)
#define MFMA32(a, b, c) __builtin_amdgcn_mfma_f32_32x32x16_bf16((a), (b), (c), 0, 0, 0)

// ---------------- K0: weight prep (transpose to [out][in], bf16) ------------
__global__ void k_prep(const float* __restrict__ w2, const float* __restrict__ qw,
                       const float* __restrict__ kw, const float* __restrict__ vw,
                       unsigned short* __restrict__ wt)
{
    int tid = blockIdx.x * 256 + threadIdx.x;   // 2048 threads
    for (int idx = tid; idx < 4096; idx += 2048) {
        int o = idx >> 6, i = idx & 63;
        wt[idx]         = f2bf(w2[i * 64 + o]);
        wt[4096 + idx]  = f2bf(qw[i * 64 + o] * QSCALE);
        wt[8192 + idx]  = f2bf(kw[i * 64 + o]);
        wt[12288 + idx] = f2bf(vw[i * 64 + o]);
    }
}

// ---------------- K1: encoder + QKV -----------------------------------------
__global__ __launch_bounds__(256)
void k_encode(const float* __restrict__ meas, const float* __restrict__ w1,
              const float* __restrict__ b1, const float* __restrict__ b2,
              const float* __restrict__ qb, const float* __restrict__ kb,
              const float* __restrict__ vb,
              const unsigned short* __restrict__ wt,
              float* __restrict__ feat,
              unsigned short* __restrict__ qbf, unsigned short* __restrict__ kbf,
              unsigned short* __restrict__ vt)
{
    __shared__ __align__(16) unsigned short hbuf[4][1152];   // 16 rows x 72
    int tid = threadIdx.x;
    int w = tid >> 6, lane = tid & 63;
    int g = lane >> 4, c16 = lane & 15;
    int m0 = (blockIdx.x * 4 + w) * 16;          // global row base (b*2048+m)
    int b  = m0 >> 11;
    unsigned short* hb = hbuf[w];
    int vrow = lane >> 2, vseg = lane & 3;       // vectorized-store mapping

    // ---- h1 directly in A-fragment layout ----
    float x[5];
    const float* xr = meas + (size_t)(m0 + c16) * 5;
#pragma unroll
    for (int i = 0; i < 5; ++i) x[i] = xr[i];
    s16x8 aH[2];
#pragma unroll
    for (int s = 0; s < 2; ++s) {
#pragma unroll
        for (int jj = 0; jj < 8; ++jj) {
            int j = 8 * g + jj + 32 * s;
            float acc = b1[j];
#pragma unroll
            for (int i = 0; i < 5; ++i) acc += x[i] * w1[i * 64 + j];
            aH[s][jj] = (short)f2bf(fmaxf(acc, 0.f));
        }
    }

    const f32x4 zero = {0.f, 0.f, 0.f, 0.f};
    f32x4 c[4];

    // ---- h2 = relu(h1 @ W2 + b2) ----
#pragma unroll
    for (int dt = 0; dt < 4; ++dt) {
        c[dt] = zero;
#pragma unroll
        for (int s = 0; s < 2; ++s) {
            s16x8 bf = *(const s16x8*)(wt + (c16 + 16 * dt) * 64 + 32 * s + 8 * g);
            c[dt] = MFMA16(aH[s], bf, c[dt]);
        }
    }
#pragma unroll
    for (int dt = 0; dt < 4; ++dt) {
        int d = c16 + 16 * dt;
        float bias = b2[d];
#pragma unroll
        for (int r = 0; r < 4; ++r) {
            float v = fmaxf(c[dt][r] + bias, 0.f);
            feat[(size_t)(m0 + 4 * g + r) * 64 + d] = v;
            hb[(4 * g + r) * 72 + d] = f2bf(v);
        }
    }
    s16x8 aF[2];
#pragma unroll
    for (int s = 0; s < 2; ++s)
        aF[s] = *(const s16x8*)(hb + c16 * 72 + 32 * s + 8 * g);

    auto gemmW = [&](const unsigned short* wmat, f32x4* cc) {
#pragma unroll
        for (int dt = 0; dt < 4; ++dt) {
            cc[dt] = zero;
#pragma unroll
            for (int s = 0; s < 2; ++s) {
                s16x8 bf = *(const s16x8*)(wmat + (c16 + 16 * dt) * 64 + 32 * s + 8 * g);
                cc[dt] = MFMA16(aF[s], bf, cc[dt]);
            }
        }
    };
    // write C-tile (plus bias) to wave-private LDS, then 2x16B coalesced store
    auto storeV = [&](const float* bias4, unsigned short* dstbase) {
#pragma unroll
        for (int dt = 0; dt < 4; ++dt) {
            int d = c16 + 16 * dt;
#pragma unroll
            for (int r = 0; r < 4; ++r)
                hb[(4 * g + r) * 72 + d] = f2bf(c[dt][r] + bias4[dt]);
        }
        s16x8 o0 = *(const s16x8*)(hb + vrow * 72 + vseg * 16);
        s16x8 o1 = *(const s16x8*)(hb + vrow * 72 + vseg * 16 + 8);
        unsigned short* dst = dstbase + (size_t)(m0 + vrow) * 64 + vseg * 16;
        *(s16x8*)dst = o0;
        *(s16x8*)(dst + 8) = o1;
    };

    float bias4[4];
    // ---- q (pre-scaled) ----
    gemmW(wt + 4096, c);
#pragma unroll
    for (int dt = 0; dt < 4; ++dt) bias4[dt] = qb[c16 + 16 * dt] * QSCALE;
    storeV(bias4, qbf);
    // ---- k ----
    gemmW(wt + 8192, c);
#pragma unroll
    for (int dt = 0; dt < 4; ++dt) bias4[dt] = kb[c16 + 16 * dt];
    storeV(bias4, kbf);
    // ---- v: compute, transpose through LDS, store vt[b][d][m] ----
    gemmW(wt + 12288, c);
#pragma unroll
    for (int dt = 0; dt < 4; ++dt) {
        int d = c16 + 16 * dt;
        float bias = vb[d];
#pragma unroll
        for (int r = 0; r < 4; ++r)
            hb[(4 * g + r) * 72 + d] = f2bf(c[dt][r] + bias);
    }
    unsigned short tvv[16];
#pragma unroll
    for (int mr = 0; mr < 16; ++mr) tvv[mr] = hb[mr * 72 + lane];   // column d=lane
    s16x8 v0, v1;
#pragma unroll
    for (int e2 = 0; e2 < 8; ++e2) { v0[e2] = (short)tvv[e2]; v1[e2] = (short)tvv[8 + e2]; }
    unsigned short* dst = vt + ((size_t)b * 64 + lane) * 2048 + (m0 & 2047);
    *(s16x8*)dst = v0;
    *(s16x8*)(dst + 8) = v1;
}

// ---------------- K2: flash attention + fused a1/tag epilogue ---------------
// 512 blocks x 512 thr (8 waves). K-loop identical to round-11 (proven 46us).
// Epilogue: split-K merge into LDS fls[128][68] + residual (preloaded), a1
// MLP with WAVE-UNIFORM weight indices (scalar cache), tag partials.
__global__ __launch_bounds__(512, 4)
void k_attn(const unsigned short* __restrict__ qbf, const unsigned short* __restrict__ kbf,
            const unsigned short* __restrict__ vt, const float* __restrict__ feat,
            const int* __restrict__ map,
            const float* __restrict__ a1w1, const float* __restrict__ a1b1,
            const float* __restrict__ a1w2, const float* __restrict__ a1b2,
            float* __restrict__ part1, float* __restrict__ part0)
{
    __shared__ __align__(16) char smem[52480];
    // loop:     K[3][64][64]bf16 @0 (24576), V[3][64][64]bf16 @24576 (24576)
    // epilogue: fls[128][68]f32 @0 (34816), Ml[4][32] @34816 (512),
    //           es[128] @35328 (512), scratch @35840:
    //             phase A: sred[4][128] (2048)
    //             phase B: accv[8][8][64] (16384) + s0r[8][8] @52224 (256)

    int tid = threadIdx.x;
    int w_ = tid >> 6, lane = tid & 63;
    int h = lane >> 5, c32 = lane & 31;
    int jhalf = w_ & 1, tile = w_ >> 1;
    int bid = (int)blockIdx.x;
    bid = (bid & 7) * 64 + (bid >> 3);           // XCD-aware swizzle (bijective)
    int b = bid >> 4;
    int chunk = bid & 15;
    int q0g = chunk * 128 + tile * 32;
    size_t rowbase = (size_t)b * 2048;

    const unsigned short* kbf_b = kbf + rowbase * 64;
    const unsigned short* vt_b  = vt + (size_t)b * 64 * 2048;

    s16x8 qf[4];
    {
        const unsigned short* qp = qbf + (rowbase + q0g + c32) * 64 + 8 * h;
#pragma unroll
        for (int st = 0; st < 4; ++st)
            qf[st] = *(const s16x8*)(qp + 16 * st);
    }

    f32x16 zero16;
#pragma unroll
    for (int i = 0; i < 16; ++i) zero16[i] = 0.f;

    f32x16 o[2];
#pragma unroll
    for (int dt = 0; dt < 2; ++dt)
#pragma unroll
        for (int i = 0; i < 16; ++i) o[dt][i] = 0.f;
    float ll = 0.f;

    int srow = 8 * w_ + (lane >> 3);
    int scol = (lane & 7) ^ (srow & 7);
    const unsigned short* gk0 = kbf_b + (size_t)srow * 64 + scol * 8;
    const unsigned short* gv0 = vt_b + (size_t)srow * 2048 + scol * 8;

    auto stage = [&](int kt, int buf) {
        gload_lds16(gk0 + (size_t)kt * 4096, smem + buf * 8192 + w_ * 1024);
        gload_lds16(gv0 + kt * 64, smem + 24576 + buf * 8192 + w_ * 1024);
    };

    int swz = c32 & 7;
    int krow = 32 * jhalf + c32;

    auto compute = [&](int buf) {
        const char* Kb = smem + buf * 8192;
        const char* Vb = smem + 24576 + buf * 8192;

        s16x8 kf[4], vf[2][2];
#pragma unroll
        for (int st = 0; st < 4; ++st)
            kf[st] = *(const s16x8*)(Kb + krow * 128 + (((2 * st + h) ^ swz) * 16));
#pragma unroll
        for (int ks = 0; ks < 2; ++ks)
#pragma unroll
            for (int dt = 0; dt < 2; ++dt)
                vf[ks][dt] = *(const s16x8*)(Vb + (32 * dt + c32) * 128 +
                                             (((4 * jhalf + 2 * ks + h) ^ swz) * 16));

        __builtin_amdgcn_s_setprio(1);
        f32x16 sc = MFMA32(kf[0], qf[0], zero16);
#pragma unroll
        for (int st = 1; st < 4; ++st)
            sc = MFMA32(kf[st], qf[st], sc);
        __builtin_amdgcn_s_setprio(0);

        float p[16];
#pragma unroll
        for (int i = 0; i < 16; ++i) p[i] = exp2_raw(sc[i]);

        float s;
        {
            float a0 = p[0] + p[1],  a1 = p[2] + p[3],  a2 = p[4] + p[5],  a3 = p[6] + p[7];
            float a4 = p[8] + p[9],  a5 = p[10] + p[11], a6 = p[12] + p[13], a7 = p[14] + p[15];
            float b0 = a0 + a1, b1 = a2 + a3, b2 = a4 + a5, b3 = a6 + a7;
            s = (b0 + b1) + (b2 + b3);
        }
        {
            float s1 = s, s2 = s;
            PLSWAP(s1, s2);
            s = s1 + s2;
        }
        ll += s;

        unsigned u[8];
#pragma unroll
        for (int k2 = 0; k2 < 8; ++k2) u[k2] = cvtpk(p[2 * k2], p[2 * k2 + 1]);

        __builtin_amdgcn_s_setprio(1);
#pragma unroll
        for (int ks = 0; ks < 2; ++ks) {
            unsigned a0 = u[4 * ks + 0], b0 = u[4 * ks + 2];
            unsigned a1 = u[4 * ks + 1], b1 = u[4 * ks + 3];
            PLSWAP(a0, b0);
            PLSWAP(a1, b1);
            union { unsigned uu[4]; s16x8 v; } pa;
            pa.uu[0] = a0; pa.uu[1] = a1; pa.uu[2] = b0; pa.uu[3] = b1;
#pragma unroll
            for (int dt = 0; dt < 2; ++dt)
                o[dt] = MFMA32(pa.v, vf[ks][dt], o[dt]);
        }
        __builtin_amdgcn_s_setprio(0);
    };

    // prologue: 2 tiles in flight; wait only the oldest (tile 0)
    stage(0, 0);
    stage(1, 1);
    WAITBAR(2);

#pragma unroll 3
    for (int kt = 0; kt < 30; ++kt) {
        stage(kt + 2, (kt + 2) % 3);
        compute(kt % 3);
        WAITBAR(2);     // retire tile kt+1's loads; tile kt+2's stay in flight
    }
    compute(0);          // tile 30 (30%3==0)
    WAITBAR(0);          // retire tile 31's loads
    compute(1);          // tile 31 (31%3==1)

    // residual preload: issue global loads BEFORE the merge barriers so the
    // L2/L3 latency hides under merge step 1.
    float resid[2][16];
    if (!jhalf) {
#pragma unroll
        for (int dt = 0; dt < 2; ++dt)
#pragma unroll
            for (int rg = 0; rg < 4; ++rg)
#pragma unroll
                for (int r = 0; r < 4; ++r) {
                    int row = tile * 32 + r + 8 * rg + 4 * h;
                    size_t fi = (rowbase + chunk * 128 + row) * 64 + 32 * dt + c32;
                    resid[dt][4 * rg + r] = feat[fi];
                }
    }
    __syncthreads();     // LDS reuse for epilogue

    // ---- fused epilogue ----
    float* fls = (float*)smem;                 // [128][68]
    float* Ml  = (float*)(smem + 34816);       // [4][32]
    float* es  = (float*)(smem + 35328);       // [128]
    float* sred = (float*)(smem + 35840);      // [4][128]   (phase A)
    float* accv = (float*)(smem + 35840);      // [8][8][64] (phase B)
    float* s0r  = (float*)(smem + 52224);      // [8][8]     (phase B)

    // merge step 1: jhalf waves publish partial O and l
    if (jhalf) {
#pragma unroll
        for (int dt = 0; dt < 2; ++dt)
#pragma unroll
            for (int rg = 0; rg < 4; ++rg)
#pragma unroll
                for (int r = 0; r < 4; ++r) {
                    int row = tile * 32 + r + 8 * rg + 4 * h;
                    fls[row * 68 + 32 * dt + c32] = o[dt][4 * rg + r];
                }
        if (h == 0) Ml[tile * 32 + c32] = ll;
    }
    __syncthreads();
    // merge step 2: !jhalf combines, normalizes, adds residual -> feat_total in LDS
    if (!jhalf) {
        float l1 = Ml[tile * 32 + c32];
        float f = 1.f / (ll + l1);
        float fr[16];
#pragma unroll
        for (int r = 0; r < 16; ++r) {
            int qrow = (r & 3) + 8 * (r >> 2) + 4 * h;
            fr[r] = __shfl(f, qrow);
        }
#pragma unroll
        for (int dt = 0; dt < 2; ++dt)
#pragma unroll
            for (int rg = 0; rg < 4; ++rg)
#pragma unroll
                for (int r = 0; r < 4; ++r) {
                    int rr = 4 * rg + r;
                    int row = tile * 32 + r + 8 * rg + 4 * h;
                    float val = (o[dt][rr] + fls[row * 68 + 32 * dt + c32]) * fr[rr]
                              + resid[dt][rr];
                    fls[row * 68 + 32 * dt + c32] = val;
                }
    }
    __syncthreads();

    // phase A: a1 per row. Wave-uniform hidden-quarter jqw = w_&3 -> weight
    // addresses are wave-uniform (s_load, scalar cache). Rows: lane + 64*(w_>>2).
    {
        int jqw = w_ & 3;
        int row = (w_ >> 2) * 64 + lane;
        const float* wbase = a1w1 + jqw * 8;            // wave-uniform
        const float* frw = &fls[row * 68];
        float acc[8];
#pragma unroll
        for (int j8 = 0; j8 < 8; ++j8) acc[j8] = 0.f;
#pragma unroll
        for (int kc = 0; kc < 16; ++kc) {
            f32x4 fv = *(const f32x4*)&frw[kc * 4];
#pragma unroll
            for (int ki = 0; ki < 4; ++ki) {
                const float* wr = wbase + (kc * 4 + ki) * 32;   // wave-uniform
#pragma unroll
                for (int j8 = 0; j8 < 8; ++j8)
                    acc[j8] = fmaf(fv[ki], wr[j8], acc[j8]);
            }
        }
        float s = 0.f;
#pragma unroll
        for (int j8 = 0; j8 < 8; ++j8)
            s += fmaxf(acc[j8] + a1b1[jqw * 8 + j8], 0.f) * a1w2[jqw * 8 + j8];
        sred[jqw * 128 + row] = s;
    }
    __syncthreads();
    if (tid < 128) {
        float a1v = sred[tid] + sred[128 + tid] + sred[256 + tid] + sred[384 + tid];
        es[tid] = exp2_raw((a1v + a1b2[0]) * LOG2E);
    }
    __syncthreads();

    // phase B: unnormalized weighted-feat partials per tag
    {
        const int* mp = map + b * 2048 + chunk * 128;
        float tacc[8], s0t[8];
#pragma unroll
        for (int t = 0; t < 8; ++t) { tacc[t] = 0.f; s0t[t] = 0.f; }
        for (int mi = w_; mi < 128; mi += 8) {
            int tg = mp[mi];
            float e = es[mi];
            float wf = e * fls[mi * 68 + lane];
#pragma unroll
            for (int t = 0; t < 8; ++t)
                if (tg == t) { tacc[t] += wf; s0t[t] += e; }
        }
#pragma unroll
        for (int t = 0; t < 8; ++t) accv[(w_ * 8 + t) * 64 + lane] = tacc[t];
        if (lane == 0) {
#pragma unroll
            for (int t = 0; t < 8; ++t) s0r[w_ * 8 + t] = s0t[t];
        }
    }
    __syncthreads();
    {
        int e = tid;            // 512 threads -> one element each
        float sum = 0.f;
#pragma unroll
        for (int w8 = 0; w8 < 8; ++w8) sum += accv[w8 * 512 + e];
        part1[((size_t)chunk * 32 + b) * 512 + e] = sum;
        if (tid < 8) {
            float s = 0.f;
#pragma unroll
            for (int w8 = 0; w8 < 8; ++w8) s += s0r[w8 * 8 + tid];
            part0[((size_t)chunk * 32 + b) * 8 + tid] = s;
        }
    }
}

// ---------------- K3: reduce partials + a2 head + outputs -------------------
__global__ __launch_bounds__(256)
void k_head(const float* __restrict__ part1, const float* __restrict__ part0,
            const float* __restrict__ a2w1, const float* __restrict__ a2b1,
            const float* __restrict__ a2w2, const float* __restrict__ a2b2,
            const float* __restrict__ muw, const float* __restrict__ mub,
            const float* __restrict__ lLw, const float* __restrict__ lLb,
            float* __restrict__ out)
{
    __shared__ float tf[8][64];
    __shared__ float deni[8];
    __shared__ float sc8[8];
    __shared__ float pose[64];
    int b = blockIdx.x;
    int tid = threadIdx.x;

    if (tid < 8) {
        float s = 0.f;
#pragma unroll
        for (int c = 0; c < 16; ++c) s += part0[((size_t)c * 32 + b) * 8 + tid];
        deni[tid] = 1.f / s;
    }
    __syncthreads();
    for (int e = tid; e < 512; e += 256) {
        float s = 0.f;
#pragma unroll
        for (int c = 0; c < 16; ++c) s += part1[((size_t)c * 32 + b) * 512 + e];
        tf[e >> 6][e & 63] = s * deni[e >> 6];
    }
    __syncthreads();

    {
        int t = tid >> 5, j = tid & 31;
        float acc = a2b1[j];
        for (int d = 0; d < 64; ++d) acc += tf[t][d] * a2w1[d * 32 + j];
        float hsum = fmaxf(acc, 0.f) * a2w2[j];
        hsum += __shfl_xor(hsum, 1);
        hsum += __shfl_xor(hsum, 2);
        hsum += __shfl_xor(hsum, 4);
        hsum += __shfl_xor(hsum, 8);
        hsum += __shfl_xor(hsum, 16);
        if (j == 0) sc8[t] = hsum + a2b2[0];
    }
    __syncthreads();
    if (tid < 64) {
        float smax = sc8[0];
#pragma unroll
        for (int t = 1; t < 8; ++t) smax = fmaxf(smax, sc8[t]);
        float e[8], ssum = 0.f;
#pragma unroll
        for (int t = 0; t < 8; ++t) { e[t] = exp2f((sc8[t] - smax) * LOG2E); ssum += e[t]; }
        float rinv = 1.f / ssum;
        float p = 0.f;
#pragma unroll
        for (int t = 0; t < 8; ++t) p += (e[t] * rinv) * tf[t][tid];
        pose[tid] = p;
    }
    __syncthreads();
    if (tid < 3) {
        float acc = mub[tid];
        for (int d = 0; d < 64; ++d) acc += pose[d] * muw[d * 3 + tid];
        out[b * 3 + tid] = acc;
    }
    if (tid >= 32 && tid < 38) {
        int oo = tid - 32;
        float acc = lLb[oo];
        for (int d = 0; d < 64; ++d) acc += pose[d] * lLw[d * 6 + oo];
        out[96 + b * 6 + oo] = acc;
    }
}

// ---------------------------------------------------------------------------
extern "C" void kernel_launch(void* const* d_in, const int* in_sizes, int n_in,
                              void* d_out, int out_size, void* d_ws, size_t ws_size,
                              hipStream_t stream)
{
    (void)in_sizes; (void)n_in; (void)out_size; (void)ws_size;

    const float* measurements = (const float*)d_in[0];
    const int*   mapping      = (const int*)d_in[1];
    const float* me_w1 = (const float*)d_in[2];
    const float* me_b1 = (const float*)d_in[3];
    const float* me_w2 = (const float*)d_in[4];
    const float* me_b2 = (const float*)d_in[5];
    const float* q_w   = (const float*)d_in[6];
    const float* q_b   = (const float*)d_in[7];
    const float* k_w   = (const float*)d_in[8];
    const float* k_b   = (const float*)d_in[9];
    const float* v_w   = (const float*)d_in[10];
    const float* v_b   = (const float*)d_in[11];
    const float* a1_w1 = (const float*)d_in[12];
    const float* a1_b1 = (const float*)d_in[13];
    const float* a1_w2 = (const float*)d_in[14];
    const float* a1_b2 = (const float*)d_in[15];
    const float* a2_w1 = (const float*)d_in[16];
    const float* a2_b1 = (const float*)d_in[17];
    const float* a2_w2 = (const float*)d_in[18];
    const float* a2_b2 = (const float*)d_in[19];
    const float* mu_w  = (const float*)d_in[20];
    const float* mu_b  = (const float*)d_in[21];
    const float* logL_w = (const float*)d_in[22];
    const float* logL_b = (const float*)d_in[23];

    char* ws = (char*)d_ws;
    unsigned short* wt    = (unsigned short*)(ws);                 // 32768 B
    float*          feat  = (float*)(ws + 40960);                  // 16 MB
    unsigned short* qbf   = (unsigned short*)(ws + 16818176);      // 8 MB
    unsigned short* kbf   = (unsigned short*)(ws + 25206784);      // 8 MB
    unsigned short* vt    = (unsigned short*)(ws + 33595392);      // 8 MB [b][d][m]
    float*          part1 = (float*)(ws + 42248192);               // 1 MB
    float*          part0 = (float*)(ws + 43296768);               // 16 KB
    float*          out   = (float*)d_out;

    k_prep<<<8, 256, 0, stream>>>(me_w2, q_w, k_w, v_w, wt);
    k_encode<<<1024, 256, 0, stream>>>(measurements, me_w1, me_b1, me_b2, q_b, k_b, v_b,
                                       wt, feat, qbf, kbf, vt);
    k_attn<<<512, 512, 0, stream>>>(qbf, kbf, vt, feat, mapping,
                                    a1_w1, a1_b1, a1_w2, a1_b2, part1, part0);
    k_head<<<32, 256, 0, stream>>>(part1, part0, a2_w1, a2_b1, a2_w2, a2_b2,
                                   mu_w, mu_b, logL_w, logL_b, out);
}

// Round 18
// 103.196 us; speedup vs baseline: 2.3990x; 1.0452x over previous
//
#include <hip/hip_runtime.h>
#include <hip/hip_bf16.h>
#include <cstdint>
#include <cstddef>

// ---------------------------------------------------------------------------
// UWBPoseEncoder: B=32, M=2048, T=8, H=64
// prep-weights -> encoder(h1,h2,q,k,v MFMA) -> flash-attn (round-11 K-loop,
// fused epilogue: split-K merge in LDS + residual + a1 MLP (readfirstlane-
// scalarized weights -> s_load) + unnormalized tag partials) -> head
// ---------------------------------------------------------------------------

typedef short s16x8 __attribute__((ext_vector_type(8)));
typedef float f32x4 __attribute__((ext_vector_type(4)));
typedef float f32x16 __attribute__((ext_vector_type(16)));

#define LOG2E  1.4426950408889634f
#define QSCALE 0.18033688011112042f   /* 0.125 * log2(e) */

__device__ __forceinline__ unsigned short f2bf(float f) {
    unsigned u = __builtin_bit_cast(unsigned, f);
    u += 0x7fffu + ((u >> 16) & 1u);          // RNE truncate to bf16
    return (unsigned short)(u >> 16);
}

__device__ __forceinline__ unsigned cvtpk(float lo, float hi) {
    unsigned r;
    asm("v_cvt_pk_bf16_f32 %0, %1, %2" : "=v"(r) : "v"(lo), "v"(hi));
    return r;
}

__device__ __forceinline__ float exp2_raw(float x) {
    float r;
    asm("v_exp_f32 %0, %1" : "=v"(r) : "v"(x));
    return r;
}

// swaps upper 32 lanes of a with lower 32 lanes of b
#define PLSWAP(a, b) asm("v_permlane32_swap_b32 %0, %1" : "+v"(a), "+v"(b))

// counted-vmcnt barrier: leave N newest vmem ops in flight across the barrier
#define WAITBAR(N) do { \
    asm volatile("s_waitcnt vmcnt(" #N ")\n\ts_barrier" ::: "memory"); \
    __builtin_amdgcn_sched_barrier(0); \
} while (0)

__device__ __forceinline__ void gload_lds16(const void* g, void* l) {
    __builtin_amdgcn_global_load_lds((const __attribute__((address_space(1))) void*)g,
                                     (__attribute__((address_space(3))) void*)l, 16, 0, 0);
}

#define MFMA16(a, b, c) __builtin_amdgcn_mfma_f32_16x16x32_bf16((a), (b), (c), 0, 0, 0)
#define MFMA32(a, b, c) __builtin_amdgcn_mfma_f32_32x32x16_bf16((a), (b), (c), 0, 0, 0)

// ---------------- K0: weight prep (transpose to [out][in], bf16) ------------
__global__ void k_prep(const float* __restrict__ w2, const float* __restrict__ qw,
                       const float* __restrict__ kw, const float* __restrict__ vw,
                       unsigned short* __restrict__ wt)
{
    int tid = blockIdx.x * 256 + threadIdx.x;   // 2048 threads
    for (int idx = tid; idx < 4096; idx += 2048) {
        int o = idx >> 6, i = idx & 63;
        wt[idx]         = f2bf(w2[i * 64 + o]);
        wt[4096 + idx]  = f2bf(qw[i * 64 + o] * QSCALE);
        wt[8192 + idx]  = f2bf(kw[i * 64 + o]);
        wt[12288 + idx] = f2bf(vw[i * 64 + o]);
    }
}

// ---------------- K1: encoder + QKV -----------------------------------------
__global__ __launch_bounds__(256)
void k_encode(const float* __restrict__ meas, const float* __restrict__ w1,
              const float* __restrict__ b1, const float* __restrict__ b2,
              const float* __restrict__ qb, const float* __restrict__ kb,
              const float* __restrict__ vb,
              const unsigned short* __restrict__ wt,
              float* __restrict__ feat,
              unsigned short* __restrict__ qbf, unsigned short* __restrict__ kbf,
              unsigned short* __restrict__ vt)
{
    __shared__ __align__(16) unsigned short hbuf[4][1152];   // 16 rows x 72
    int tid = threadIdx.x;
    int w = tid >> 6, lane = tid & 63;
    int g = lane >> 4, c16 = lane & 15;
    int m0 = (blockIdx.x * 4 + w) * 16;          // global row base (b*2048+m)
    int b  = m0 >> 11;
    unsigned short* hb = hbuf[w];
    int vrow = lane >> 2, vseg = lane & 3;       // vectorized-store mapping

    // ---- h1 directly in A-fragment layout ----
    float x[5];
    const float* xr = meas + (size_t)(m0 + c16) * 5;
#pragma unroll
    for (int i = 0; i < 5; ++i) x[i] = xr[i];
    s16x8 aH[2];
#pragma unroll
    for (int s = 0; s < 2; ++s) {
#pragma unroll
        for (int jj = 0; jj < 8; ++jj) {
            int j = 8 * g + jj + 32 * s;
            float acc = b1[j];
#pragma unroll
            for (int i = 0; i < 5; ++i) acc += x[i] * w1[i * 64 + j];
            aH[s][jj] = (short)f2bf(fmaxf(acc, 0.f));
        }
    }

    const f32x4 zero = {0.f, 0.f, 0.f, 0.f};
    f32x4 c[4];

    // ---- h2 = relu(h1 @ W2 + b2) ----
#pragma unroll
    for (int dt = 0; dt < 4; ++dt) {
        c[dt] = zero;
#pragma unroll
        for (int s = 0; s < 2; ++s) {
            s16x8 bf = *(const s16x8*)(wt + (c16 + 16 * dt) * 64 + 32 * s + 8 * g);
            c[dt] = MFMA16(aH[s], bf, c[dt]);
        }
    }
#pragma unroll
    for (int dt = 0; dt < 4; ++dt) {
        int d = c16 + 16 * dt;
        float bias = b2[d];
#pragma unroll
        for (int r = 0; r < 4; ++r) {
            float v = fmaxf(c[dt][r] + bias, 0.f);
            feat[(size_t)(m0 + 4 * g + r) * 64 + d] = v;
            hb[(4 * g + r) * 72 + d] = f2bf(v);
        }
    }
    s16x8 aF[2];
#pragma unroll
    for (int s = 0; s < 2; ++s)
        aF[s] = *(const s16x8*)(hb + c16 * 72 + 32 * s + 8 * g);

    auto gemmW = [&](const unsigned short* wmat, f32x4* cc) {
#pragma unroll
        for (int dt = 0; dt < 4; ++dt) {
            cc[dt] = zero;
#pragma unroll
            for (int s = 0; s < 2; ++s) {
                s16x8 bf = *(const s16x8*)(wmat + (c16 + 16 * dt) * 64 + 32 * s + 8 * g);
                cc[dt] = MFMA16(aF[s], bf, cc[dt]);
            }
        }
    };
    // write C-tile (plus bias) to wave-private LDS, then 2x16B coalesced store
    auto storeV = [&](const float* bias4, unsigned short* dstbase) {
#pragma unroll
        for (int dt = 0; dt < 4; ++dt) {
            int d = c16 + 16 * dt;
#pragma unroll
            for (int r = 0; r < 4; ++r)
                hb[(4 * g + r) * 72 + d] = f2bf(c[dt][r] + bias4[dt]);
        }
        s16x8 o0 = *(const s16x8*)(hb + vrow * 72 + vseg * 16);
        s16x8 o1 = *(const s16x8*)(hb + vrow * 72 + vseg * 16 + 8);
        unsigned short* dst = dstbase + (size_t)(m0 + vrow) * 64 + vseg * 16;
        *(s16x8*)dst = o0;
        *(s16x8*)(dst + 8) = o1;
    };

    float bias4[4];
    // ---- q (pre-scaled) ----
    gemmW(wt + 4096, c);
#pragma unroll
    for (int dt = 0; dt < 4; ++dt) bias4[dt] = qb[c16 + 16 * dt] * QSCALE;
    storeV(bias4, qbf);
    // ---- k ----
    gemmW(wt + 8192, c);
#pragma unroll
    for (int dt = 0; dt < 4; ++dt) bias4[dt] = kb[c16 + 16 * dt];
    storeV(bias4, kbf);
    // ---- v: compute, transpose through LDS, store vt[b][d][m] ----
    gemmW(wt + 12288, c);
#pragma unroll
    for (int dt = 0; dt < 4; ++dt) {
        int d = c16 + 16 * dt;
        float bias = vb[d];
#pragma unroll
        for (int r = 0; r < 4; ++r)
            hb[(4 * g + r) * 72 + d] = f2bf(c[dt][r] + bias);
    }
    unsigned short tvv[16];
#pragma unroll
    for (int mr = 0; mr < 16; ++mr) tvv[mr] = hb[mr * 72 + lane];   // column d=lane
    s16x8 v0, v1;
#pragma unroll
    for (int e2 = 0; e2 < 8; ++e2) { v0[e2] = (short)tvv[e2]; v1[e2] = (short)tvv[8 + e2]; }
    unsigned short* dst = vt + ((size_t)b * 64 + lane) * 2048 + (m0 & 2047);
    *(s16x8*)dst = v0;
    *(s16x8*)(dst + 8) = v1;
}

// ---------------- K2: flash attention + fused a1/tag epilogue ---------------
// 512 blocks x 512 thr (8 waves). K-loop identical to round-11 (proven 46us).
// Epilogue: split-K merge into LDS fls[128][68] + residual (preloaded), a1
// MLP with readfirstlane-scalarized weights (s_load), tag partials.
__global__ __launch_bounds__(512, 4)
void k_attn(const unsigned short* __restrict__ qbf, const unsigned short* __restrict__ kbf,
            const unsigned short* __restrict__ vt, const float* __restrict__ feat,
            const int* __restrict__ map,
            const float* __restrict__ a1w1, const float* __restrict__ a1b1,
            const float* __restrict__ a1w2, const float* __restrict__ a1b2,
            float* __restrict__ part1, float* __restrict__ part0)
{
    __shared__ __align__(16) char smem[52480];
    // loop:     K[3][64][64]bf16 @0 (24576), V[3][64][64]bf16 @24576 (24576)
    // epilogue: fls[128][68]f32 @0 (34816), Ml[4][32] @34816 (512),
    //           es[128] @35328 (512), scratch @35840:
    //             phase A: sred[4][128] (2048)
    //             phase B: accv[8][8][64] (16384) + s0r[8][8] @52224 (256)

    int tid = threadIdx.x;
    int w_ = tid >> 6, lane = tid & 63;
    int h = lane >> 5, c32 = lane & 31;
    int jhalf = w_ & 1, tile = w_ >> 1;
    int bid = (int)blockIdx.x;
    bid = (bid & 7) * 64 + (bid >> 3);           // XCD-aware swizzle (bijective)
    int b = bid >> 4;
    int chunk = bid & 15;
    int q0g = chunk * 128 + tile * 32;
    size_t rowbase = (size_t)b * 2048;

    const unsigned short* kbf_b = kbf + rowbase * 64;
    const unsigned short* vt_b  = vt + (size_t)b * 64 * 2048;

    s16x8 qf[4];
    {
        const unsigned short* qp = qbf + (rowbase + q0g + c32) * 64 + 8 * h;
#pragma unroll
        for (int st = 0; st < 4; ++st)
            qf[st] = *(const s16x8*)(qp + 16 * st);
    }

    f32x16 zero16;
#pragma unroll
    for (int i = 0; i < 16; ++i) zero16[i] = 0.f;

    f32x16 o[2];
#pragma unroll
    for (int dt = 0; dt < 2; ++dt)
#pragma unroll
        for (int i = 0; i < 16; ++i) o[dt][i] = 0.f;
    float ll = 0.f;

    int srow = 8 * w_ + (lane >> 3);
    int scol = (lane & 7) ^ (srow & 7);
    const unsigned short* gk0 = kbf_b + (size_t)srow * 64 + scol * 8;
    const unsigned short* gv0 = vt_b + (size_t)srow * 2048 + scol * 8;

    auto stage = [&](int kt, int buf) {
        gload_lds16(gk0 + (size_t)kt * 4096, smem + buf * 8192 + w_ * 1024);
        gload_lds16(gv0 + kt * 64, smem + 24576 + buf * 8192 + w_ * 1024);
    };

    int swz = c32 & 7;
    int krow = 32 * jhalf + c32;

    auto compute = [&](int buf) {
        const char* Kb = smem + buf * 8192;
        const char* Vb = smem + 24576 + buf * 8192;

        s16x8 kf[4], vf[2][2];
#pragma unroll
        for (int st = 0; st < 4; ++st)
            kf[st] = *(const s16x8*)(Kb + krow * 128 + (((2 * st + h) ^ swz) * 16));
#pragma unroll
        for (int ks = 0; ks < 2; ++ks)
#pragma unroll
            for (int dt = 0; dt < 2; ++dt)
                vf[ks][dt] = *(const s16x8*)(Vb + (32 * dt + c32) * 128 +
                                             (((4 * jhalf + 2 * ks + h) ^ swz) * 16));

        __builtin_amdgcn_s_setprio(1);
        f32x16 sc = MFMA32(kf[0], qf[0], zero16);
#pragma unroll
        for (int st = 1; st < 4; ++st)
            sc = MFMA32(kf[st], qf[st], sc);
        __builtin_amdgcn_s_setprio(0);

        float p[16];
#pragma unroll
        for (int i = 0; i < 16; ++i) p[i] = exp2_raw(sc[i]);

        float s;
        {
            float a0 = p[0] + p[1],  a1 = p[2] + p[3],  a2 = p[4] + p[5],  a3 = p[6] + p[7];
            float a4 = p[8] + p[9],  a5 = p[10] + p[11], a6 = p[12] + p[13], a7 = p[14] + p[15];
            float b0 = a0 + a1, b1 = a2 + a3, b2 = a4 + a5, b3 = a6 + a7;
            s = (b0 + b1) + (b2 + b3);
        }
        {
            float s1 = s, s2 = s;
            PLSWAP(s1, s2);
            s = s1 + s2;
        }
        ll += s;

        unsigned u[8];
#pragma unroll
        for (int k2 = 0; k2 < 8; ++k2) u[k2] = cvtpk(p[2 * k2], p[2 * k2 + 1]);

        __builtin_amdgcn_s_setprio(1);
#pragma unroll
        for (int ks = 0; ks < 2; ++ks) {
            unsigned a0 = u[4 * ks + 0], b0 = u[4 * ks + 2];
            unsigned a1 = u[4 * ks + 1], b1 = u[4 * ks + 3];
            PLSWAP(a0, b0);
            PLSWAP(a1, b1);
            union { unsigned uu[4]; s16x8 v; } pa;
            pa.uu[0] = a0; pa.uu[1] = a1; pa.uu[2] = b0; pa.uu[3] = b1;
#pragma unroll
            for (int dt = 0; dt < 2; ++dt)
                o[dt] = MFMA32(pa.v, vf[ks][dt], o[dt]);
        }
        __builtin_amdgcn_s_setprio(0);
    };

    // prologue: 2 tiles in flight; wait only the oldest (tile 0)
    stage(0, 0);
    stage(1, 1);
    WAITBAR(2);

#pragma unroll 3
    for (int kt = 0; kt < 30; ++kt) {
        stage(kt + 2, (kt + 2) % 3);
        compute(kt % 3);
        WAITBAR(2);     // retire tile kt+1's loads; tile kt+2's stay in flight
    }
    compute(0);          // tile 30 (30%3==0)
    WAITBAR(0);          // retire tile 31's loads
    compute(1);          // tile 31 (31%3==1)

    // residual preload: issue global loads BEFORE the merge barriers so the
    // L2/L3 latency hides under merge step 1.
    float resid[2][16];
    if (!jhalf) {
#pragma unroll
        for (int dt = 0; dt < 2; ++dt)
#pragma unroll
            for (int rg = 0; rg < 4; ++rg)
#pragma unroll
                for (int r = 0; r < 4; ++r) {
                    int row = tile * 32 + r + 8 * rg + 4 * h;
                    size_t fi = (rowbase + chunk * 128 + row) * 64 + 32 * dt + c32;
                    resid[dt][4 * rg + r] = feat[fi];
                }
    }
    __syncthreads();     // LDS reuse for epilogue

    // ---- fused epilogue ----
    float* fls = (float*)smem;                 // [128][68]
    float* Ml  = (float*)(smem + 34816);       // [4][32]
    float* es  = (float*)(smem + 35328);       // [128]
    float* sred = (float*)(smem + 35840);      // [4][128]   (phase A)
    float* accv = (float*)(smem + 35840);      // [8][8][64] (phase B)
    float* s0r  = (float*)(smem + 52224);      // [8][8]     (phase B)

    // merge step 1: jhalf waves publish partial O and l
    if (jhalf) {
#pragma unroll
        for (int dt = 0; dt < 2; ++dt)
#pragma unroll
            for (int rg = 0; rg < 4; ++rg)
#pragma unroll
                for (int r = 0; r < 4; ++r) {
                    int row = tile * 32 + r + 8 * rg + 4 * h;
                    fls[row * 68 + 32 * dt + c32] = o[dt][4 * rg + r];
                }
        if (h == 0) Ml[tile * 32 + c32] = ll;
    }
    __syncthreads();
    // merge step 2: !jhalf combines, normalizes, adds residual -> feat_total in LDS
    if (!jhalf) {
        float l1 = Ml[tile * 32 + c32];
        float f = 1.f / (ll + l1);
        float fr[16];
#pragma unroll
        for (int r = 0; r < 16; ++r) {
            int qrow = (r & 3) + 8 * (r >> 2) + 4 * h;
            fr[r] = __shfl(f, qrow);
        }
#pragma unroll
        for (int dt = 0; dt < 2; ++dt)
#pragma unroll
            for (int rg = 0; rg < 4; ++rg)
#pragma unroll
                for (int r = 0; r < 4; ++r) {
                    int rr = 4 * rg + r;
                    int row = tile * 32 + r + 8 * rg + 4 * h;
                    float val = (o[dt][rr] + fls[row * 68 + 32 * dt + c32]) * fr[rr]
                              + resid[dt][rr];
                    fls[row * 68 + 32 * dt + c32] = val;
                }
    }
    __syncthreads();

    // phase A: a1 per row. readfirstlane FORCES wave-uniform SGPR indices so
    // all weight/bias accesses compile to s_load (scalar cache), not VMEM.
    {
        int jqw = __builtin_amdgcn_readfirstlane(w_ & 3);
        int rgrp = __builtin_amdgcn_readfirstlane(w_ >> 2);
        int row = rgrp * 64 + lane;
        const float* wbase = a1w1 + jqw * 8;            // SGPR base
        const float* frw = &fls[row * 68];
        float acc[8];
#pragma unroll
        for (int j8 = 0; j8 < 8; ++j8) acc[j8] = 0.f;
#pragma unroll
        for (int kc = 0; kc < 16; ++kc) {
            f32x4 fv = *(const f32x4*)&frw[kc * 4];
#pragma unroll
            for (int ki = 0; ki < 4; ++ki) {
                const float* wr = wbase + (kc * 4 + ki) * 32;   // SGPR + imm
#pragma unroll
                for (int j8 = 0; j8 < 8; ++j8)
                    acc[j8] = fmaf(fv[ki], wr[j8], acc[j8]);
            }
        }
        float s = 0.f;
#pragma unroll
        for (int j8 = 0; j8 < 8; ++j8)
            s += fmaxf(acc[j8] + a1b1[jqw * 8 + j8], 0.f) * a1w2[jqw * 8 + j8];
        sred[jqw * 128 + row] = s;
    }
    __syncthreads();
    if (tid < 128) {
        float a1v = sred[tid] + sred[128 + tid] + sred[256 + tid] + sred[384 + tid];
        es[tid] = exp2_raw((a1v + a1b2[0]) * LOG2E);
    }
    __syncthreads();

    // phase B: unnormalized weighted-feat partials per tag (scalarized map loads)
    {
        int wu = __builtin_amdgcn_readfirstlane(w_);
        const int* mp = map + b * 2048 + chunk * 128;
        float tacc[8], s0t[8];
#pragma unroll
        for (int t = 0; t < 8; ++t) { tacc[t] = 0.f; s0t[t] = 0.f; }
#pragma unroll
        for (int i = 0; i < 16; ++i) {
            int mi = wu + 8 * i;
            int tg = mp[mi];                      // uniform addr -> s_load
            float e = es[mi];
            float wf = e * fls[mi * 68 + lane];
#pragma unroll
            for (int t = 0; t < 8; ++t)
                if (tg == t) { tacc[t] += wf; s0t[t] += e; }
        }
#pragma unroll
        for (int t = 0; t < 8; ++t) accv[(wu * 8 + t) * 64 + lane] = tacc[t];
        if (lane == 0) {
#pragma unroll
            for (int t = 0; t < 8; ++t) s0r[wu * 8 + t] = s0t[t];
        }
    }
    __syncthreads();
    {
        int e = tid;            // 512 threads -> one element each
        float sum = 0.f;
#pragma unroll
        for (int w8 = 0; w8 < 8; ++w8) sum += accv[w8 * 512 + e];
        part1[((size_t)chunk * 32 + b) * 512 + e] = sum;
        if (tid < 8) {
            float s = 0.f;
#pragma unroll
            for (int w8 = 0; w8 < 8; ++w8) s += s0r[w8 * 8 + tid];
            part0[((size_t)chunk * 32 + b) * 8 + tid] = s;
        }
    }
}

// ---------------- K3: reduce partials + a2 head + outputs -------------------
__global__ __launch_bounds__(256)
void k_head(const float* __restrict__ part1, const float* __restrict__ part0,
            const float* __restrict__ a2w1, const float* __restrict__ a2b1,
            const float* __restrict__ a2w2, const float* __restrict__ a2b2,
            const float* __restrict__ muw, const float* __restrict__ mub,
            const float* __restrict__ lLw, const float* __restrict__ lLb,
            float* __restrict__ out)
{
    __shared__ float tf[8][64];
    __shared__ float deni[8];
    __shared__ float sc8[8];
    __shared__ float pose[64];
    int b = blockIdx.x;
    int tid = threadIdx.x;

    if (tid < 8) {
        float s = 0.f;
#pragma unroll
        for (int c = 0; c < 16; ++c) s += part0[((size_t)c * 32 + b) * 8 + tid];
        deni[tid] = 1.f / s;
    }
    __syncthreads();
    for (int e = tid; e < 512; e += 256) {
        float s = 0.f;
#pragma unroll
        for (int c = 0; c < 16; ++c) s += part1[((size_t)c * 32 + b) * 512 + e];
        tf[e >> 6][e & 63] = s * deni[e >> 6];
    }
    __syncthreads();

    {
        int t = tid >> 5, j = tid & 31;
        float acc = a2b1[j];
        for (int d = 0; d < 64; ++d) acc += tf[t][d] * a2w1[d * 32 + j];
        float hsum = fmaxf(acc, 0.f) * a2w2[j];
        hsum += __shfl_xor(hsum, 1);
        hsum += __shfl_xor(hsum, 2);
        hsum += __shfl_xor(hsum, 4);
        hsum += __shfl_xor(hsum, 8);
        hsum += __shfl_xor(hsum, 16);
        if (j == 0) sc8[t] = hsum + a2b2[0];
    }
    __syncthreads();
    if (tid < 64) {
        float smax = sc8[0];
#pragma unroll
        for (int t = 1; t < 8; ++t) smax = fmaxf(smax, sc8[t]);
        float e[8], ssum = 0.f;
#pragma unroll
        for (int t = 0; t < 8; ++t) { e[t] = exp2f((sc8[t] - smax) * LOG2E); ssum += e[t]; }
        float rinv = 1.f / ssum;
        float p = 0.f;
#pragma unroll
        for (int t = 0; t < 8; ++t) p += (e[t] * rinv) * tf[t][tid];
        pose[tid] = p;
    }
    __syncthreads();
    if (tid < 3) {
        float acc = mub[tid];
        for (int d = 0; d < 64; ++d) acc += pose[d] * muw[d * 3 + tid];
        out[b * 3 + tid] = acc;
    }
    if (tid >= 32 && tid < 38) {
        int oo = tid - 32;
        float acc = lLb[oo];
        for (int d = 0; d < 64; ++d) acc += pose[d] * lLw[d * 6 + oo];
        out[96 + b * 6 + oo] = acc;
    }
}

// ---------------------------------------------------------------------------
extern "C" void kernel_launch(void* const* d_in, const int* in_sizes, int n_in,
                              void* d_out, int out_size, void* d_ws, size_t ws_size,
                              hipStream_t stream)
{
    (void)in_sizes; (void)n_in; (void)out_size; (void)ws_size;

    const float* measurements = (const float*)d_in[0];
    const int*   mapping      = (const int*)d_in[1];
    const float* me_w1 = (const float*)d_in[2];
    const float* me_b1 = (const float*)d_in[3];
    const float* me_w2 = (const float*)d_in[4];
    const float* me_b2 = (const float*)d_in[5];
    const float* q_w   = (const float*)d_in[6];
    const float* q_b   = (const float*)d_in[7];
    const float* k_w   = (const float*)d_in[8];
    const float* k_b   = (const float*)d_in[9];
    const float* v_w   = (const float*)d_in[10];
    const float* v_b   = (const float*)d_in[11];
    const float* a1_w1 = (const float*)d_in[12];
    const float* a1_b1 = (const float*)d_in[13];
    const float* a1_w2 = (const float*)d_in[14];
    const float* a1_b2 = (const float*)d_in[15];
    const float* a2_w1 = (const float*)d_in[16];
    const float* a2_b1 = (const float*)d_in[17];
    const float* a2_w2 = (const float*)d_in[18];
    const float* a2_b2 = (const float*)d_in[19];
    const float* mu_w  = (const float*)d_in[20];
    const float* mu_b  = (const float*)d_in[21];
    const float* logL_w = (const float*)d_in[22];
    const float* logL_b = (const float*)d_in[23];

    char* ws = (char*)d_ws;
    unsigned short* wt    = (unsigned short*)(ws);                 // 32768 B
    float*          feat  = (float*)(ws + 40960);                  // 16 MB
    unsigned short* qbf   = (unsigned short*)(ws + 16818176);      // 8 MB
    unsigned short* kbf   = (unsigned short*)(ws + 25206784);      // 8 MB
    unsigned short* vt    = (unsigned short*)(ws + 33595392);      // 8 MB [b][d][m]
    float*          part1 = (float*)(ws + 42248192);               // 1 MB
    float*          part0 = (float*)(ws + 43296768);               // 16 KB
    float*          out   = (float*)d_out;

    k_prep<<<8, 256, 0, stream>>>(me_w2, q_w, k_w, v_w, wt);
    k_encode<<<1024, 256, 0, stream>>>(measurements, me_w1, me_b1, me_b2, q_b, k_b, v_b,
                                       wt, feat, qbf, kbf, vt);
    k_attn<<<512, 512, 0, stream>>>(qbf, kbf, vt, feat, mapping,
                                    a1_w1, a1_b1, a1_w2, a1_b2, part1, part0);
    k_head<<<32, 256, 0, stream>>>(part1, part0, a2_w1, a2_b1, a2_w2, a2_b2,
                                   mu_w, mu_b, logL_w, logL_b, out);
}